// Round 11
// baseline (381.734 us; speedup 1.0000x reference)
//
#include <hip/hip_runtime.h>

// CrissCrossAttention: B=8 C=512 CQ=128 H=W=96
// out = g*(Wv·xAgg + bv) + x, xAgg = attW·x + attH·x (linearity of V-path).
// ws layout (EXACTLY 189,530,112 B — round-1-proven cap):
//  @0          : xT[p][512]bf16 75,497,472 (k1->k2a) THEN xAgg[p][512]bf16 (k6->k9)
//  @75,497,472 : xP[b][c][h][w]bf16 75,497,472 (k1->k9: k6<0> B-tile + k9 epilogue)
//  @150,994,944: Qb[p][128]bf16 18,874,368 (k2a->k4); after k4: att2 bf16[p][192] 28,311,552 (k5->k6)
//  @169,869,312: Kb[p][128]bf16 18,874,368 (k2a->k4)
//  @188,743,680: Wqk bf16[256][512]; @189,005,824: Wvb bf16[512][512]; end 189,530,112
// d_out scratch until k9 (poisoned-ok, fully rewritten):
//  @0          : attf fp16[p][192] 28,311,552 (k4->k5)
//  @75,497,472 : xPT[b][c][w][h]bf16 75,497,472 (k3->k6<1>)

#define B_ 8
#define C_ 512
#define CQ_ 128
#define H_ 96
#define W_ 96
#define HW_ 9216
#define J_ 192

typedef __attribute__((ext_vector_type(8))) short short8;
typedef __attribute__((ext_vector_type(4))) float f32x4;

__device__ __forceinline__ unsigned short f2bf(float f) {
    unsigned u = __float_as_uint(f);
    u += 0x7FFFu + ((u >> 16) & 1u);
    return (unsigned short)(u >> 16);
}
__device__ __forceinline__ float bf2f(unsigned short h) {
    return __uint_as_float((unsigned)h << 16);
}
__device__ __forceinline__ unsigned short f2h(float f) {
    _Float16 h = (_Float16)f;
    return __builtin_bit_cast(unsigned short, h);
}
__device__ __forceinline__ float h2f(unsigned short u) {
    return (float)__builtin_bit_cast(_Float16, u);
}
__device__ __forceinline__ void gl_lds16(const unsigned short* g, void* lds_base) {
    __builtin_amdgcn_global_load_lds((const __attribute__((address_space(1))) void*)g,
                                     (__attribute__((address_space(3))) void*)lds_base,
                                     16, 0, 0);
}

// ---------------- K0: weights fp32 -> bf16 ----------------
__global__ __launch_bounds__(256) void k0_wconv(const float* __restrict__ Wq,
                                                const float* __restrict__ Wk,
                                                const float* __restrict__ Wv,
                                                unsigned short* __restrict__ Wqk,
                                                unsigned short* __restrict__ Wvb) {
    int i = blockIdx.x * 256 + threadIdx.x;
    if (i < 65536)        Wqk[i] = f2bf(Wq[i]);
    else if (i < 131072)  Wqk[i] = f2bf(Wk[i - 65536]);
    else                  Wvb[i - 131072] = f2bf(Wv[i - 131072]);
}

// ---------------- K1: x f32 -> xT[b][hw][c] bf16  AND  xP[b][c][hw] bf16 ----------------
__global__ __launch_bounds__(256) void k1_xT(const float* __restrict__ x,
                                             unsigned short* __restrict__ xT,
                                             unsigned short* __restrict__ xP) {
    __shared__ unsigned short t[32][33];
    int b = blockIdx.z, c0 = blockIdx.y * 32, p0 = blockIdx.x * 32;
    int tx = threadIdx.x, ty = threadIdx.y;
    const float* xb = x + (size_t)b * C_ * HW_;
    #pragma unroll
    for (int k = 0; k < 4; ++k) {
        int c = c0 + ty + k * 8;
        unsigned short v = f2bf(xb[(size_t)c * HW_ + p0 + tx]);
        t[ty + k * 8][tx] = v;
        xP[((size_t)b * C_ + c) * HW_ + p0 + tx] = v;
    }
    __syncthreads();
    unsigned short* xTb = xT + (size_t)b * HW_ * C_;
    #pragma unroll
    for (int k = 0; k < 4; ++k) {
        int p = p0 + ty + k * 8;
        xTb[(size_t)p * C_ + c0 + tx] = t[tx][ty + k * 8];
    }
}

// ---------------- K3: plane transpose bf16: src[b][c][h][w] -> dst[b][c][w][h] ----------------
__global__ __launch_bounds__(256) void k3_vt(const unsigned short* __restrict__ src_,
                                             unsigned short* __restrict__ dst_) {
    __shared__ unsigned short tl[96][97];
    int plane = blockIdx.x;
    const unsigned short* src = src_ + (size_t)plane * HW_;
    unsigned short* dst = dst_ + (size_t)plane * HW_;
    for (int e = threadIdx.x; e < HW_; e += 256) tl[e / 96][e % 96] = src[e];
    __syncthreads();
    for (int e = threadIdx.x; e < HW_; e += 256) { int w = e / 96, h = e % 96; dst[e] = tl[h][w]; }
}

// ---------------- K2a: Q,K projection, swizzled gl_lds staging ----------------
// BM=128(p) BN=256(oc) BK=64, 8 waves (2x4 of 64x64)
__global__ __launch_bounds__(512) void k2a_qk(const unsigned short* __restrict__ xT,
                                              const unsigned short* __restrict__ Wqk,
                                              const float* __restrict__ bq,
                                              const float* __restrict__ bk,
                                              unsigned short* __restrict__ Qb,
                                              unsigned short* __restrict__ Kb) {
    __shared__ alignas(16) unsigned short As[128][64];
    __shared__ alignas(16) unsigned short Bs[256][64];
    int t = threadIdx.x;
    int p0 = blockIdx.x * 128;
    int wid = t >> 6, lane = t & 63;
    int wr = wid >> 2, wc = wid & 3;
    int srow = lane >> 3;
    int sk8 = (((lane & 7) ^ srow) << 3);            // pre-swizzled global chunk
    const f32x4 zero = {0.f, 0.f, 0.f, 0.f};
    f32x4 acc[4][4];
    for (int m = 0; m < 4; ++m) for (int n = 0; n < 4; ++n) acc[m][n] = zero;
    for (int ks = 0; ks < 512; ks += 64) {
        #pragma unroll
        for (int i = 0; i < 2; ++i) {
            int q = wid * 2 + i; int row = q * 8 + srow;
            gl_lds16(xT + ((size_t)(p0 + row) << 9) + ks + sk8, (char*)&As[0][0] + q * 1024);
        }
        #pragma unroll
        for (int i = 0; i < 4; ++i) {
            int q = wid * 4 + i; int row = q * 8 + srow;
            gl_lds16(Wqk + ((size_t)row << 9) + ks + sk8, (char*)&Bs[0][0] + q * 1024);
        }
        __syncthreads();
        #pragma unroll
        for (int kk = 0; kk < 2; ++kk) {
            int po = (((kk * 4 + (lane >> 4)) ^ (lane & 7)) << 3);   // swizzled read offset
            short8 af[4], bfv[4];
            #pragma unroll
            for (int m = 0; m < 4; ++m) af[m] = *(const short8*)(&As[wr * 64 + m * 16 + (lane & 15)][po]);
            #pragma unroll
            for (int n = 0; n < 4; ++n) bfv[n] = *(const short8*)(&Bs[wc * 64 + n * 16 + (lane & 15)][po]);
            #pragma unroll
            for (int m = 0; m < 4; ++m)
                #pragma unroll
                for (int n = 0; n < 4; ++n)
                    acc[m][n] = __builtin_amdgcn_mfma_f32_16x16x32_bf16(af[m], bfv[n], acc[m][n], 0, 0, 0);
        }
        __syncthreads();
    }
    #pragma unroll
    for (int n = 0; n < 4; ++n) {
        int oc = wc * 64 + n * 16 + (lane & 15);
        float bias = (oc < 128) ? bq[oc] : bk[oc - 128];
        unsigned short* dst = (oc < 128) ? (Qb + oc) : (Kb + (oc - 128));
        #pragma unroll
        for (int m = 0; m < 4; ++m) {
            int pr = p0 + wr * 64 + m * 16 + ((lane >> 4) << 2);
            #pragma unroll
            for (int r = 0; r < 4; ++r)
                dst[(size_t)(pr + r) << 7] = f2bf(acc[m][n][r] + bias);
        }
    }
}

// ---------------- K4: energies (fp16 out). z=0: E_W; z=1: E_H (diag=-inf) ----------------
__global__ __launch_bounds__(256) void k4_energy(const unsigned short* __restrict__ Qb,
                                                 const unsigned short* __restrict__ Kb,
                                                 unsigned short* __restrict__ att) {
    __shared__ alignas(16) unsigned short Qs[96][136];
    __shared__ alignas(16) unsigned short Ks[96][136];
    int t = threadIdx.x;
    int modeH = blockIdx.z;
    int b = blockIdx.y, v0 = blockIdx.x;
    size_t base, rstride, obase_off, ostride;
    if (!modeH) {
        base      = (size_t)((b * H_ + v0) * W_) * CQ_;
        rstride   = CQ_;
        obase_off = (size_t)((b * H_ + v0) * W_) * J_ + H_;
        ostride   = J_;
    } else {
        base      = ((size_t)(b * H_) * W_ + v0) * CQ_;
        rstride   = (size_t)W_ * CQ_;
        obase_off = ((size_t)(b * H_) * W_ + v0) * J_;
        ostride   = (size_t)W_ * J_;
    }
    for (int q = t; q < 1536; q += 256) {
        int row = q >> 4, c8 = (q & 15) << 3;
        *(uint4*)(&Qs[row][c8]) = *(const uint4*)(Qb + base + (size_t)row * rstride + c8);
        *(uint4*)(&Ks[row][c8]) = *(const uint4*)(Kb + base + (size_t)row * rstride + c8);
    }
    __syncthreads();
    int wid = t >> 6, lane = t & 63;
    int wr = wid >> 1, wc = wid & 1;
    const f32x4 zero = {0.f, 0.f, 0.f, 0.f};
    f32x4 acc[3][3];
    for (int m = 0; m < 3; ++m) for (int n = 0; n < 3; ++n) acc[m][n] = zero;
    #pragma unroll
    for (int ks = 0; ks < 128; ks += 32) {
        int ko = ks + ((lane >> 4) << 3);
        short8 af[3], bfv[3];
        #pragma unroll
        for (int m = 0; m < 3; ++m) af[m] = *(const short8*)(&Qs[wr * 48 + m * 16 + (lane & 15)][ko]);
        #pragma unroll
        for (int n = 0; n < 3; ++n) bfv[n] = *(const short8*)(&Ks[wc * 48 + n * 16 + (lane & 15)][ko]);
        #pragma unroll
        for (int m = 0; m < 3; ++m)
            #pragma unroll
            for (int n = 0; n < 3; ++n)
                acc[m][n] = __builtin_amdgcn_mfma_f32_16x16x32_bf16(af[m], bfv[n], acc[m][n], 0, 0, 0);
    }
    unsigned short* ob = att + obase_off;
    #pragma unroll
    for (int m = 0; m < 3; ++m) {
        int i = wr * 48 + m * 16 + ((lane >> 4) << 2);
        #pragma unroll
        for (int n = 0; n < 3; ++n) {
            int j = wc * 48 + n * 16 + (lane & 15);
            #pragma unroll
            for (int r = 0; r < 4; ++r) {
                float v = acc[m][n][r];
                if (modeH && (i + r) == j) v = -__builtin_inff();
                ob[(size_t)(i + r) * ostride + j] = f2h(v);
            }
        }
    }
}

// ---------------- K5: softmax over 192 (fp16 in) -> bf16 att2 ----------------
__global__ __launch_bounds__(256) void k5_softmax(const unsigned short* __restrict__ att,
                                                  unsigned short* __restrict__ att2) {
    int r = blockIdx.x * 4 + (threadIdx.x >> 6);
    int lane = threadIdx.x & 63;
    const unsigned short* row = att + (size_t)r * J_;
    float e0 = h2f(row[lane]), e1 = h2f(row[lane + 64]), e2 = h2f(row[lane + 128]);
    float m = fmaxf(e0, fmaxf(e1, e2));
    #pragma unroll
    for (int off = 32; off; off >>= 1) m = fmaxf(m, __shfl_xor(m, off, 64));
    float p0 = __expf(e0 - m), p1 = __expf(e1 - m), p2 = __expf(e2 - m);
    float s = p0 + p1 + p2;
    #pragma unroll
    for (int off = 32; off; off >>= 1) s += __shfl_xor(s, off, 64);
    float inv = 1.f / s;
    unsigned short* orow = att2 + (size_t)r * J_;
    orow[lane]       = f2bf(p0 * inv);
    orow[lane + 64]  = f2bf(p1 * inv);
    orow[lane + 128] = f2bf(p2 * inv);
}

// ---------------- K6: x-aggregation. D[row][c] = sum_j A[row][j] * Xsrc[c][v*96+j] ----------------
// MODE 0 (W-dir): per (b, h=v): A=attW rows w; Xsrc=xP.   D[w][c] -> xAgg (overwrite)
// MODE 1 (H-dir): per (b, w=v): A=attH rows h; Xsrc=xPT.  D[h][c] -> xAgg (+= accumulate)
template <int MODE>
__global__ __launch_bounds__(512) void k6_agg(const unsigned short* __restrict__ att2,
                                              const unsigned short* __restrict__ Xsrc,
                                              unsigned short* __restrict__ xAgg) {
    __shared__ alignas(16) unsigned short As[96][104];
    __shared__ alignas(16) unsigned short Bs[256][104];
    int t = threadIdx.x;
    int c0 = blockIdx.x * 256;
    int b = blockIdx.y / 96;
    int v = blockIdx.y % 96;
    size_t abase, astride;
    if (MODE == 0) { abase = ((size_t)(b * HW_) + (size_t)v * 96) * J_ + 96; astride = J_; }
    else           { abase = (size_t)(b * HW_) * J_ + (size_t)v * J_;        astride = (size_t)96 * J_; }
    if (t < 192) {
        int row = t >> 1, cs = (t & 1) * 6;
        const unsigned short* src = att2 + abase + (size_t)row * astride;
        #pragma unroll
        for (int i = 0; i < 6; ++i)
            *(uint4*)(&As[row][(cs + i) * 8]) = *(const uint4*)(src + (cs + i) * 8);
    }
    {
        int row = t >> 1, cs = (t & 1) * 6;
        const unsigned short* src = Xsrc + ((size_t)(b * C_) + c0 + row) * HW_ + v * 96;
        #pragma unroll
        for (int i = 0; i < 6; ++i)
            *(uint4*)(&Bs[row][(cs + i) * 8]) = *(const uint4*)(src + (cs + i) * 8);
    }
    __syncthreads();
    int wid = t >> 6, lane = t & 63;
    int wr = wid >> 2, wc = wid & 3;                 // 2(m:48) x 4(n:64)
    const f32x4 zero = {0.f, 0.f, 0.f, 0.f};
    f32x4 acc[3][4];
    for (int m = 0; m < 3; ++m) for (int n = 0; n < 4; ++n) acc[m][n] = zero;
    #pragma unroll
    for (int ks = 0; ks < 96; ks += 32) {
        int ko = ks + ((lane >> 4) << 3);
        short8 af[3], bfv[4];
        #pragma unroll
        for (int m = 0; m < 3; ++m) af[m] = *(const short8*)(&As[wr * 48 + m * 16 + (lane & 15)][ko]);
        #pragma unroll
        for (int n = 0; n < 4; ++n) bfv[n] = *(const short8*)(&Bs[wc * 64 + n * 16 + (lane & 15)][ko]);
        #pragma unroll
        for (int m = 0; m < 3; ++m)
            #pragma unroll
            for (int n = 0; n < 4; ++n)
                acc[m][n] = __builtin_amdgcn_mfma_f32_16x16x32_bf16(af[m], bfv[n], acc[m][n], 0, 0, 0);
    }
    #pragma unroll
    for (int m = 0; m < 3; ++m) {
        int orow = wr * 48 + m * 16 + ((lane >> 4) << 2);
        #pragma unroll
        for (int n = 0; n < 4; ++n) {
            int c = c0 + wc * 64 + n * 16 + (lane & 15);
            #pragma unroll
            for (int r = 0; r < 4; ++r) {
                int p = (MODE == 0) ? (v * 96 + orow + r) : ((orow + r) * 96 + v);
                size_t o = ((size_t)(b * HW_) + p) * C_ + c;
                if (MODE == 0) xAgg[o] = f2bf(acc[m][n][r]);
                else           xAgg[o] = f2bf(bf2f(xAgg[o]) + acc[m][n][r]);
            }
        }
    }
}

// ---------------- K9: fused projection + epilogue, BM=256 BN=128 BK=32 dbuf + LDS-bounce epilogue ----------------
// D[oc][p] = sum_k Wv[oc][k]*xAgg[p][k]; out[b][oc][p] = g*(D+bv[oc]) + bf2f(xP[b][oc][p])
// 512 thr / 8 waves (2oc x 4p; wave = 128oc x 32p), acc 8x2. LDS 48KB -> 3 blocks/CU.
// xAgg (L3-resident) staged 512/256=2x (was 4x); Wv staged 576x but L2-resident.
// Epilogue: two 128-row halves through 32KB LDS-bounce, fully coalesced dwordx4 stores.
__global__ __launch_bounds__(512) void k9_proj(const unsigned short* __restrict__ xAgg,
                                               const unsigned short* __restrict__ Wvb,
                                               const float* __restrict__ bv,
                                               const unsigned short* __restrict__ xPb,
                                               const float* __restrict__ gamma_p,
                                               float* __restrict__ outp) {
    __shared__ alignas(16) char smem[49152];
    unsigned short* AsBase = (unsigned short*)smem;            // [2][256][32] = 32 KB
    unsigned short* BsBase = (unsigned short*)(smem + 32768);  // [2][128][32] = 16 KB
    int t = threadIdx.x;
    int bid = blockIdx.x;
    int tile = (bid & 7) * 144 + (bid >> 3);             // XCD-chunked remap (1152 = 8*144)
    int oc0 = (tile & 1) * 256;
    int pt  = tile >> 1;                                 // 0..575
    int p0  = pt * 128;
    int wid = t >> 6, lane = t & 63;
    int wr = wid >> 2, wc = wid & 3;                     // 2(oc:128) x 4(p:32)
    int srow = lane >> 2;                                // chunk: 16 rows x 32 cols = 1KB
    int sk8 = (((lane & 3) ^ (srow & 3)) << 3);          // XOR swizzle within 4 col-groups
    const f32x4 zero = {0.f, 0.f, 0.f, 0.f};
    f32x4 acc[8][2];
    for (int m = 0; m < 8; ++m) for (int n = 0; n < 2; ++n) acc[m][n] = zero;

    // stage one BK=32 tile pair: A 16 chunks (2/wave) + B 8 chunks (1/wave) = 3 gl_lds/wave
    auto STAGE = [&](int buf, int ks) {
        #pragma unroll
        for (int i = 0; i < 2; ++i) {
            int q = wid * 2 + i; int row = q * 16 + srow;
            gl_lds16(Wvb + ((size_t)(oc0 + row) << 9) + ks + sk8,
                     smem + buf * 16384 + q * 1024);
        }
        {
            int q = wid; int row = q * 16 + srow;
            gl_lds16(xAgg + ((size_t)(p0 + row) << 9) + ks + sk8,
                     smem + 32768 + buf * 8192 + q * 1024);
        }
    };

    STAGE(0, 0);
    #pragma unroll
    for (int step = 0; step < 16; ++step) {
        int cur = step & 1;
        if (step < 15) {
            STAGE(cur ^ 1, (step + 1) * 32);             // prefetch next tile
            asm volatile("s_waitcnt vmcnt(3)" ::: "memory");   // cur's 3 loads done; next's in flight
        } else {
            asm volatile("s_waitcnt vmcnt(0)" ::: "memory");
        }
        __builtin_amdgcn_s_barrier();
        __builtin_amdgcn_sched_barrier(0);
        {
            short8 af[8], bfv[2];
            #pragma unroll
            for (int m = 0; m < 8; ++m) {
                int row = wr * 128 + m * 16 + (lane & 15);
                int po = (((lane >> 4) ^ (row & 3)) << 3);
                af[m] = *(const short8*)(AsBase + cur * 8192 + row * 32 + po);
            }
            #pragma unroll
            for (int n = 0; n < 2; ++n) {
                int row = wc * 32 + n * 16 + (lane & 15);
                int po = (((lane >> 4) ^ (row & 3)) << 3);
                bfv[n] = *(const short8*)(BsBase + cur * 4096 + row * 32 + po);
            }
            #pragma unroll
            for (int m = 0; m < 8; ++m)
                #pragma unroll
                for (int n = 0; n < 2; ++n)
                    acc[m][n] = __builtin_amdgcn_mfma_f32_16x16x32_bf16(af[m], bfv[n], acc[m][n], 0, 0, 0);
        }
        __builtin_amdgcn_s_barrier();
    }
    __syncthreads();                                     // staging LDS dead; reuse for epilogue

    int b = pt / 72;
    int hw0 = (pt % 72) * 128;
    float g = gamma_p[0];
    #pragma unroll
    for (int half = 0; half < 2; ++half) {
        // Phase 1: waves with wr==half deposit their acc into a [128 rows][128 cols] bf16 tile
        if (wr == half) {
            #pragma unroll
            for (int m = 0; m < 8; ++m) {
                int rowb = m * 16 + ((lane >> 4) << 2);          // 0..127 within half
                #pragma unroll
                for (int r = 0; r < 4; ++r) {
                    int row = rowb + r;
                    float bias = bv[oc0 + half * 128 + row];
                    #pragma unroll
                    for (int n = 0; n < 2; ++n) {
                        int col = wc * 32 + n * 16 + (lane & 15);
                        int baddr = row * 256 + ((col << 1) ^ ((row & 7) << 4));
                        *(unsigned short*)(smem + baddr) = f2bf(acc[m][n][r] + bias);
                    }
                }
            }
        }
        __syncthreads();
        // Phase 2: all 512 threads write 128 rows x 128 cols coalesced. 8 passes x 16 rows.
        #pragma unroll
        for (int pass = 0; pass < 8; ++pass) {
            int row = pass * 16 + (t >> 5);
            int cs = (t & 31) * 4;
            uint2 tv = *(const uint2*)(smem + row * 256 + ((cs << 1) ^ ((row & 7) << 4)));
            int oc = oc0 + half * 128 + row;
            size_t o = ((size_t)(b * C_ + oc)) * HW_ + hw0 + cs;
            uint2 xv = *(const uint2*)(xPb + o);
            f32x4 ov;
            ov[0] = g * bf2f((unsigned short)(tv.x & 0xFFFF)) + bf2f((unsigned short)(xv.x & 0xFFFF));
            ov[1] = g * bf2f((unsigned short)(tv.x >> 16))    + bf2f((unsigned short)(xv.x >> 16));
            ov[2] = g * bf2f((unsigned short)(tv.y & 0xFFFF)) + bf2f((unsigned short)(xv.y & 0xFFFF));
            ov[3] = g * bf2f((unsigned short)(tv.y >> 16))    + bf2f((unsigned short)(xv.y >> 16));
            *(f32x4*)(outp + o) = ov;
        }
        __syncthreads();
    }
}

extern "C" void kernel_launch(void* const* d_in, const int* in_sizes, int n_in,
                              void* d_out, int out_size, void* d_ws, size_t ws_size,
                              hipStream_t stream) {
    const float* x  = (const float*)d_in[0];
    const float* Wq = (const float*)d_in[1];
    const float* bq = (const float*)d_in[2];
    const float* Wk = (const float*)d_in[3];
    const float* bk = (const float*)d_in[4];
    const float* Wv = (const float*)d_in[5];
    const float* bv = (const float*)d_in[6];
    const float* gm = (const float*)d_in[7];
    float* out = (float*)d_out;
    char* ws = (char*)d_ws;

    // ws (exactly 189,530,112 B)
    unsigned short* xT    = (unsigned short*)(ws + 0);
    unsigned short* xAgg  = (unsigned short*)(ws + 0);           // after k2a done
    unsigned short* xP    = (unsigned short*)(ws + 75497472);    // live k1 -> k9
    unsigned short* Qb    = (unsigned short*)(ws + 150994944);
    unsigned short* att2  = (unsigned short*)(ws + 150994944);   // after k4 done (overlays Qb/Kb)
    unsigned short* Kb    = (unsigned short*)(ws + 169869312);
    unsigned short* Wqk   = (unsigned short*)(ws + 188743680);
    unsigned short* Wvb   = (unsigned short*)(ws + 189005824);
    // d_out scratch (dead before k9 writes out)
    unsigned short* attf  = (unsigned short*)d_out;              // fp16, 28,311,552 B
    unsigned short* xPT   = (unsigned short*)((char*)d_out + 75497472);  // 75,497,472 B

    k0_wconv<<<1536, 256, 0, stream>>>(Wq, Wk, Wv, Wqk, Wvb);
    k1_xT<<<dim3(288, 16, 8), dim3(32, 8, 1), 0, stream>>>(x, xT, xP);
    k2a_qk<<<576, 512, 0, stream>>>(xT, Wqk, bq, bk, Qb, Kb);
    k3_vt<<<4096, 256, 0, stream>>>(xP, xPT);                      // xPT in d_out scratch
    k4_energy<<<dim3(96, 8, 2), 256, 0, stream>>>(Qb, Kb, attf);   // attf in d_out scratch
    k5_softmax<<<18432, 256, 0, stream>>>(attf, att2);             // att2 overlays Qb/Kb (dead)
    k6_agg<0><<<dim3(2, 768), 512, 0, stream>>>(att2, xP, xAgg);   // xAgg overlays xT (dead)
    k6_agg<1><<<dim3(2, 768), 512, 0, stream>>>(att2, xPT, xAgg);  // accumulate H-direction
    k9_proj<<<1152, 512, 0, stream>>>(xAgg, Wvb, bv, xP, gm, out);
}

// Round 12
// 364.038 us; speedup vs baseline: 1.0486x; 1.0486x over previous
//
#include <hip/hip_runtime.h>

// CrissCrossAttention: B=8 C=512 CQ=128 H=W=96
// out = g*(Wv·xAgg + bv) + x, xAgg = attW·x + attH·x (linearity of V-path).
// ws layout (EXACTLY 189,530,112 B — round-1-proven cap):
//  @0          : xT[p][512]bf16 75,497,472 (k1->k2a) THEN xAgg[p][512]bf16 (k6->k9)
//  @75,497,472 : xP[b][c][h][w]bf16 75,497,472 (k1->k9: k6<0> B-tile + k9 epilogue)
//  @150,994,944: Qb[p][128]bf16 18,874,368 (k2a->k4); after k4: att2 bf16[p][192] 28,311,552 (k5->k6)
//  @169,869,312: Kb[p][128]bf16 18,874,368 (k2a->k4)
//  @188,743,680: Wqk bf16[256][512]; @189,005,824: Wvb bf16[512][512]; end 189,530,112
// d_out scratch until k9 (poisoned-ok, fully rewritten):
//  @0          : attf fp16[p][192] 28,311,552 (k4->k5)
//  @75,497,472 : xPT[b][c][w][h]bf16 75,497,472 (k3->k6<1>)

#define B_ 8
#define C_ 512
#define CQ_ 128
#define H_ 96
#define W_ 96
#define HW_ 9216
#define J_ 192

typedef __attribute__((ext_vector_type(8))) short short8;
typedef __attribute__((ext_vector_type(4))) float f32x4;

__device__ __forceinline__ unsigned short f2bf(float f) {
    unsigned u = __float_as_uint(f);
    u += 0x7FFFu + ((u >> 16) & 1u);
    return (unsigned short)(u >> 16);
}
__device__ __forceinline__ float bf2f(unsigned short h) {
    return __uint_as_float((unsigned)h << 16);
}
__device__ __forceinline__ unsigned short f2h(float f) {
    _Float16 h = (_Float16)f;
    return __builtin_bit_cast(unsigned short, h);
}
__device__ __forceinline__ float h2f(unsigned short u) {
    return (float)__builtin_bit_cast(_Float16, u);
}
__device__ __forceinline__ void gl_lds16(const unsigned short* g, void* lds_base) {
    __builtin_amdgcn_global_load_lds((const __attribute__((address_space(1))) void*)g,
                                     (__attribute__((address_space(3))) void*)lds_base,
                                     16, 0, 0);
}

// ---------------- K0: weights fp32 -> bf16 ----------------
__global__ __launch_bounds__(256) void k0_wconv(const float* __restrict__ Wq,
                                                const float* __restrict__ Wk,
                                                const float* __restrict__ Wv,
                                                unsigned short* __restrict__ Wqk,
                                                unsigned short* __restrict__ Wvb) {
    int i = blockIdx.x * 256 + threadIdx.x;
    if (i < 65536)        Wqk[i] = f2bf(Wq[i]);
    else if (i < 131072)  Wqk[i] = f2bf(Wk[i - 65536]);
    else                  Wvb[i - 131072] = f2bf(Wv[i - 131072]);
}

// ---------------- K1: x f32 -> xT[b][hw][c] bf16  AND  xP[b][c][hw] bf16 ----------------
__global__ __launch_bounds__(256) void k1_xT(const float* __restrict__ x,
                                             unsigned short* __restrict__ xT,
                                             unsigned short* __restrict__ xP) {
    __shared__ unsigned short t[32][33];
    int b = blockIdx.z, c0 = blockIdx.y * 32, p0 = blockIdx.x * 32;
    int tx = threadIdx.x, ty = threadIdx.y;
    const float* xb = x + (size_t)b * C_ * HW_;
    #pragma unroll
    for (int k = 0; k < 4; ++k) {
        int c = c0 + ty + k * 8;
        unsigned short v = f2bf(xb[(size_t)c * HW_ + p0 + tx]);
        t[ty + k * 8][tx] = v;
        xP[((size_t)b * C_ + c) * HW_ + p0 + tx] = v;
    }
    __syncthreads();
    unsigned short* xTb = xT + (size_t)b * HW_ * C_;
    #pragma unroll
    for (int k = 0; k < 4; ++k) {
        int p = p0 + ty + k * 8;
        xTb[(size_t)p * C_ + c0 + tx] = t[tx][ty + k * 8];
    }
}

// ---------------- K3: plane transpose bf16: src[b][c][h][w] -> dst[b][c][w][h] ----------------
__global__ __launch_bounds__(256) void k3_vt(const unsigned short* __restrict__ src_,
                                             unsigned short* __restrict__ dst_) {
    __shared__ unsigned short tl[96][97];
    int plane = blockIdx.x;
    const unsigned short* src = src_ + (size_t)plane * HW_;
    unsigned short* dst = dst_ + (size_t)plane * HW_;
    for (int e = threadIdx.x; e < HW_; e += 256) tl[e / 96][e % 96] = src[e];
    __syncthreads();
    for (int e = threadIdx.x; e < HW_; e += 256) { int w = e / 96, h = e % 96; dst[e] = tl[h][w]; }
}

// ---------------- K2a: Q,K projection, BK=32 dbuf counted-vmcnt (round-8-verified pattern) ----------------
// BM=128(p) BN=256(oc), 8 waves (2p x 4oc of 64x64), LDS 48KB -> 3 blocks/CU.
__global__ __launch_bounds__(512) void k2a_qk(const unsigned short* __restrict__ xT,
                                              const unsigned short* __restrict__ Wqk,
                                              const float* __restrict__ bq,
                                              const float* __restrict__ bk,
                                              unsigned short* __restrict__ Qb,
                                              unsigned short* __restrict__ Kb) {
    __shared__ alignas(16) char smem[49152];
    unsigned short* AsBase = (unsigned short*)smem;            // [2][128][32] = 16 KB
    unsigned short* BsBase = (unsigned short*)(smem + 16384);  // [2][256][32] = 32 KB
    int t = threadIdx.x;
    int p0 = blockIdx.x * 128;
    int wid = t >> 6, lane = t & 63;
    int wr = wid >> 2, wc = wid & 3;                 // 2(p:64) x 4(oc:64)
    int srow = lane >> 2;                            // chunk: 16 rows x 32 cols = 1KB
    int sk8 = (((lane & 3) ^ (srow & 3)) << 3);      // XOR swizzle within 4 col-groups
    const f32x4 zero = {0.f, 0.f, 0.f, 0.f};
    f32x4 acc[4][4];
    for (int m = 0; m < 4; ++m) for (int n = 0; n < 4; ++n) acc[m][n] = zero;

    // stage one BK=32 tile pair: A 8 chunks (1/wave) + B 16 chunks (2/wave) = 3 gl_lds/wave
    auto STAGE = [&](int buf, int ks) {
        {
            int q = wid; int row = q * 16 + srow;
            gl_lds16(xT + ((size_t)(p0 + row) << 9) + ks + sk8,
                     smem + buf * 8192 + q * 1024);
        }
        #pragma unroll
        for (int i = 0; i < 2; ++i) {
            int q = wid * 2 + i; int row = q * 16 + srow;
            gl_lds16(Wqk + ((size_t)row << 9) + ks + sk8,
                     smem + 16384 + buf * 16384 + q * 1024);
        }
    };

    STAGE(0, 0);
    #pragma unroll
    for (int step = 0; step < 16; ++step) {
        int cur = step & 1;
        if (step < 15) {
            STAGE(cur ^ 1, (step + 1) * 32);             // prefetch next tile
            asm volatile("s_waitcnt vmcnt(3)" ::: "memory");   // cur's 3 loads done; next in flight
        } else {
            asm volatile("s_waitcnt vmcnt(0)" ::: "memory");
        }
        __builtin_amdgcn_s_barrier();
        __builtin_amdgcn_sched_barrier(0);
        {
            short8 af[4], bfv[4];
            #pragma unroll
            for (int m = 0; m < 4; ++m) {
                int row = wr * 64 + m * 16 + (lane & 15);
                int po = (((lane >> 4) ^ (row & 3)) << 3);
                af[m] = *(const short8*)(AsBase + cur * 4096 + row * 32 + po);
            }
            #pragma unroll
            for (int n = 0; n < 4; ++n) {
                int row = wc * 64 + n * 16 + (lane & 15);
                int po = (((lane >> 4) ^ (row & 3)) << 3);
                bfv[n] = *(const short8*)(BsBase + cur * 8192 + row * 32 + po);
            }
            #pragma unroll
            for (int m = 0; m < 4; ++m)
                #pragma unroll
                for (int n = 0; n < 4; ++n)
                    acc[m][n] = __builtin_amdgcn_mfma_f32_16x16x32_bf16(af[m], bfv[n], acc[m][n], 0, 0, 0);
        }
        __builtin_amdgcn_s_barrier();
    }
    #pragma unroll
    for (int n = 0; n < 4; ++n) {
        int oc = wc * 64 + n * 16 + (lane & 15);
        float bias = (oc < 128) ? bq[oc] : bk[oc - 128];
        unsigned short* dst = (oc < 128) ? (Qb + oc) : (Kb + (oc - 128));
        #pragma unroll
        for (int m = 0; m < 4; ++m) {
            int pr = p0 + wr * 64 + m * 16 + ((lane >> 4) << 2);
            #pragma unroll
            for (int r = 0; r < 4; ++r)
                dst[(size_t)(pr + r) << 7] = f2bf(acc[m][n][r] + bias);
        }
    }
}

// ---------------- K4: energies (fp16 out). z=0: E_W; z=1: E_H (diag=-inf) ----------------
__global__ __launch_bounds__(256) void k4_energy(const unsigned short* __restrict__ Qb,
                                                 const unsigned short* __restrict__ Kb,
                                                 unsigned short* __restrict__ att) {
    __shared__ alignas(16) unsigned short Qs[96][136];
    __shared__ alignas(16) unsigned short Ks[96][136];
    int t = threadIdx.x;
    int modeH = blockIdx.z;
    int b = blockIdx.y, v0 = blockIdx.x;
    size_t base, rstride, obase_off, ostride;
    if (!modeH) {
        base      = (size_t)((b * H_ + v0) * W_) * CQ_;
        rstride   = CQ_;
        obase_off = (size_t)((b * H_ + v0) * W_) * J_ + H_;
        ostride   = J_;
    } else {
        base      = ((size_t)(b * H_) * W_ + v0) * CQ_;
        rstride   = (size_t)W_ * CQ_;
        obase_off = ((size_t)(b * H_) * W_ + v0) * J_;
        ostride   = (size_t)W_ * J_;
    }
    for (int q = t; q < 1536; q += 256) {
        int row = q >> 4, c8 = (q & 15) << 3;
        *(uint4*)(&Qs[row][c8]) = *(const uint4*)(Qb + base + (size_t)row * rstride + c8);
        *(uint4*)(&Ks[row][c8]) = *(const uint4*)(Kb + base + (size_t)row * rstride + c8);
    }
    __syncthreads();
    int wid = t >> 6, lane = t & 63;
    int wr = wid >> 1, wc = wid & 1;
    const f32x4 zero = {0.f, 0.f, 0.f, 0.f};
    f32x4 acc[3][3];
    for (int m = 0; m < 3; ++m) for (int n = 0; n < 3; ++n) acc[m][n] = zero;
    #pragma unroll
    for (int ks = 0; ks < 128; ks += 32) {
        int ko = ks + ((lane >> 4) << 3);
        short8 af[3], bfv[3];
        #pragma unroll
        for (int m = 0; m < 3; ++m) af[m] = *(const short8*)(&Qs[wr * 48 + m * 16 + (lane & 15)][ko]);
        #pragma unroll
        for (int n = 0; n < 3; ++n) bfv[n] = *(const short8*)(&Ks[wc * 48 + n * 16 + (lane & 15)][ko]);
        #pragma unroll
        for (int m = 0; m < 3; ++m)
            #pragma unroll
            for (int n = 0; n < 3; ++n)
                acc[m][n] = __builtin_amdgcn_mfma_f32_16x16x32_bf16(af[m], bfv[n], acc[m][n], 0, 0, 0);
    }
    unsigned short* ob = att + obase_off;
    #pragma unroll
    for (int m = 0; m < 3; ++m) {
        int i = wr * 48 + m * 16 + ((lane >> 4) << 2);
        #pragma unroll
        for (int n = 0; n < 3; ++n) {
            int j = wc * 48 + n * 16 + (lane & 15);
            #pragma unroll
            for (int r = 0; r < 4; ++r) {
                float v = acc[m][n][r];
                if (modeH && (i + r) == j) v = -__builtin_inff();
                ob[(size_t)(i + r) * ostride + j] = f2h(v);
            }
        }
    }
}

// ---------------- K5: softmax over 192 (fp16 in) -> bf16 att2 ----------------
__global__ __launch_bounds__(256) void k5_softmax(const unsigned short* __restrict__ att,
                                                  unsigned short* __restrict__ att2) {
    int r = blockIdx.x * 4 + (threadIdx.x >> 6);
    int lane = threadIdx.x & 63;
    const unsigned short* row = att + (size_t)r * J_;
    float e0 = h2f(row[lane]), e1 = h2f(row[lane + 64]), e2 = h2f(row[lane + 128]);
    float m = fmaxf(e0, fmaxf(e1, e2));
    #pragma unroll
    for (int off = 32; off; off >>= 1) m = fmaxf(m, __shfl_xor(m, off, 64));
    float p0 = __expf(e0 - m), p1 = __expf(e1 - m), p2 = __expf(e2 - m);
    float s = p0 + p1 + p2;
    #pragma unroll
    for (int off = 32; off; off >>= 1) s += __shfl_xor(s, off, 64);
    float inv = 1.f / s;
    unsigned short* orow = att2 + (size_t)r * J_;
    orow[lane]       = f2bf(p0 * inv);
    orow[lane + 64]  = f2bf(p1 * inv);
    orow[lane + 128] = f2bf(p2 * inv);
}

// ---------------- K6: x-aggregation. D[row][c] = sum_j A[row][j] * Xsrc[c][v*96+j] ----------------
// MODE 0 (W-dir): per (b, h=v): A=attW rows w; Xsrc=xP.   D[w][c] -> xAgg (overwrite)
// MODE 1 (H-dir): per (b, w=v): A=attH rows h; Xsrc=xPT.  D[h][c] -> xAgg (+= accumulate)
template <int MODE>
__global__ __launch_bounds__(512) void k6_agg(const unsigned short* __restrict__ att2,
                                              const unsigned short* __restrict__ Xsrc,
                                              unsigned short* __restrict__ xAgg) {
    __shared__ alignas(16) unsigned short As[96][104];
    __shared__ alignas(16) unsigned short Bs[256][104];
    int t = threadIdx.x;
    int c0 = blockIdx.x * 256;
    int b = blockIdx.y / 96;
    int v = blockIdx.y % 96;
    size_t abase, astride;
    if (MODE == 0) { abase = ((size_t)(b * HW_) + (size_t)v * 96) * J_ + 96; astride = J_; }
    else           { abase = (size_t)(b * HW_) * J_ + (size_t)v * J_;        astride = (size_t)96 * J_; }
    if (t < 192) {
        int row = t >> 1, cs = (t & 1) * 6;
        const unsigned short* src = att2 + abase + (size_t)row * astride;
        #pragma unroll
        for (int i = 0; i < 6; ++i)
            *(uint4*)(&As[row][(cs + i) * 8]) = *(const uint4*)(src + (cs + i) * 8);
    }
    {
        int row = t >> 1, cs = (t & 1) * 6;
        const unsigned short* src = Xsrc + ((size_t)(b * C_) + c0 + row) * HW_ + v * 96;
        #pragma unroll
        for (int i = 0; i < 6; ++i)
            *(uint4*)(&Bs[row][(cs + i) * 8]) = *(const uint4*)(src + (cs + i) * 8);
    }
    __syncthreads();
    int wid = t >> 6, lane = t & 63;
    int wr = wid >> 2, wc = wid & 3;                 // 2(m:48) x 4(n:64)
    const f32x4 zero = {0.f, 0.f, 0.f, 0.f};
    f32x4 acc[3][4];
    for (int m = 0; m < 3; ++m) for (int n = 0; n < 4; ++n) acc[m][n] = zero;
    #pragma unroll
    for (int ks = 0; ks < 96; ks += 32) {
        int ko = ks + ((lane >> 4) << 3);
        short8 af[3], bfv[4];
        #pragma unroll
        for (int m = 0; m < 3; ++m) af[m] = *(const short8*)(&As[wr * 48 + m * 16 + (lane & 15)][ko]);
        #pragma unroll
        for (int n = 0; n < 4; ++n) bfv[n] = *(const short8*)(&Bs[wc * 64 + n * 16 + (lane & 15)][ko]);
        #pragma unroll
        for (int m = 0; m < 3; ++m)
            #pragma unroll
            for (int n = 0; n < 4; ++n)
                acc[m][n] = __builtin_amdgcn_mfma_f32_16x16x32_bf16(af[m], bfv[n], acc[m][n], 0, 0, 0);
    }
    #pragma unroll
    for (int m = 0; m < 3; ++m) {
        int orow = wr * 48 + m * 16 + ((lane >> 4) << 2);
        #pragma unroll
        for (int n = 0; n < 4; ++n) {
            int c = c0 + wc * 64 + n * 16 + (lane & 15);
            #pragma unroll
            for (int r = 0; r < 4; ++r) {
                int p = (MODE == 0) ? (v * 96 + orow + r) : ((orow + r) * 96 + v);
                size_t o = ((size_t)(b * HW_) + p) * C_ + c;
                if (MODE == 0) xAgg[o] = f2bf(acc[m][n][r]);
                else           xAgg[o] = f2bf(bf2f(xAgg[o]) + acc[m][n][r]);
            }
        }
    }
}

// ---------------- K9: fused projection + epilogue, BK=32 dbuf counted-vmcnt + LDS-bounce epilogue ----------------
// (round-10 proven config: 95.6 us)
// D[oc][p] = sum_k Wv[oc][k]*xAgg[p][k]; out[b][oc][p] = g*(D+bv[oc]) + bf2f(xP[b][oc][p])
// BM=128(oc) BN=128(p) BK=32 dbuf, 4 waves (2x2 of 64x64), LDS 32KB -> 5 blocks/CU.
__global__ __launch_bounds__(256) void k9_proj(const unsigned short* __restrict__ xAgg,
                                               const unsigned short* __restrict__ Wvb,
                                               const float* __restrict__ bv,
                                               const unsigned short* __restrict__ xPb,
                                               const float* __restrict__ gamma_p,
                                               float* __restrict__ outp) {
    __shared__ alignas(16) char smem[32768];
    unsigned short* AsBase = (unsigned short*)smem;            // [2][128][32] = 16 KB
    unsigned short* BsBase = (unsigned short*)(smem + 16384);  // [2][128][32] = 16 KB
    int t = threadIdx.x;
    int bid = blockIdx.x;
    int tile = (bid & 7) * 288 + (bid >> 3);             // XCD-chunked remap (2304 = 8*288)
    int oc0 = (tile & 3) * 128;
    int pt  = tile >> 2;                                 // 0..575
    int p0  = pt * 128;
    int wid = t >> 6, lane = t & 63;
    int wr = wid >> 1, wc = wid & 1;                     // 2(oc:64) x 2(p:64)
    int srow = lane >> 2;                                // chunk: 16 rows x 32 cols = 1KB
    int sk8 = (((lane & 3) ^ (srow & 3)) << 3);          // XOR swizzle within 4 col-groups
    const f32x4 zero = {0.f, 0.f, 0.f, 0.f};
    f32x4 acc[4][4];
    for (int m = 0; m < 4; ++m) for (int n = 0; n < 4; ++n) acc[m][n] = zero;

    auto STAGE = [&](int buf, int ks) {
        #pragma unroll
        for (int i = 0; i < 2; ++i) {
            int q = wid * 2 + i; int row = q * 16 + srow;
            gl_lds16(Wvb + ((size_t)(oc0 + row) << 9) + ks + sk8,
                     smem + buf * 8192 + q * 1024);
        }
        #pragma unroll
        for (int i = 0; i < 2; ++i) {
            int q = wid * 2 + i; int row = q * 16 + srow;
            gl_lds16(xAgg + ((size_t)(p0 + row) << 9) + ks + sk8,
                     smem + 16384 + buf * 8192 + q * 1024);
        }
    };

    STAGE(0, 0);
    #pragma unroll
    for (int step = 0; step < 16; ++step) {
        int cur = step & 1;
        if (step < 15) {
            STAGE(cur ^ 1, (step + 1) * 32);             // prefetch next tile
            asm volatile("s_waitcnt vmcnt(4)" ::: "memory");   // cur's 4 loads done
        } else {
            asm volatile("s_waitcnt vmcnt(0)" ::: "memory");
        }
        __builtin_amdgcn_s_barrier();
        __builtin_amdgcn_sched_barrier(0);
        {
            short8 af[4], bfv[4];
            #pragma unroll
            for (int m = 0; m < 4; ++m) {
                int row = wr * 64 + m * 16 + (lane & 15);
                int po = (((lane >> 4) ^ (row & 3)) << 3);
                af[m] = *(const short8*)(AsBase + cur * 4096 + row * 32 + po);
            }
            #pragma unroll
            for (int n = 0; n < 4; ++n) {
                int row = wc * 64 + n * 16 + (lane & 15);
                int po = (((lane >> 4) ^ (row & 3)) << 3);
                bfv[n] = *(const short8*)(BsBase + cur * 4096 + row * 32 + po);
            }
            #pragma unroll
            for (int m = 0; m < 4; ++m)
                #pragma unroll
                for (int n = 0; n < 4; ++n)
                    acc[m][n] = __builtin_amdgcn_mfma_f32_16x16x32_bf16(af[m], bfv[n], acc[m][n], 0, 0, 0);
        }
        __builtin_amdgcn_s_barrier();
    }
    __syncthreads();                                     // staging LDS now dead; safe to reuse

    // Phase 1: acc + bias -> bf16 tile [128 rows][128 cols], 16B-granule XOR swizzle
    #pragma unroll
    for (int m = 0; m < 4; ++m) {
        int rowb = wr * 64 + m * 16 + ((lane >> 4) << 2);
        #pragma unroll
        for (int r = 0; r < 4; ++r) {
            int row = rowb + r;
            float bias = bv[oc0 + row];
            #pragma unroll
            for (int n = 0; n < 4; ++n) {
                int col = wc * 64 + n * 16 + (lane & 15);
                int baddr = row * 256 + ((col << 1) ^ ((row & 7) << 4));
                *(unsigned short*)(smem + baddr) = f2bf(acc[m][n][r] + bias);
            }
        }
    }
    __syncthreads();

    // Phase 2: coalesced write-out. 16 passes x (8 rows x 128 cols).
    int b = pt / 72;
    int hw0 = (pt % 72) * 128;
    float g = gamma_p[0];
    #pragma unroll
    for (int pass = 0; pass < 16; ++pass) {
        int row = pass * 8 + (t >> 5);
        int cs = (t & 31) * 4;
        uint2 tv = *(const uint2*)(smem + row * 256 + ((cs << 1) ^ ((row & 7) << 4)));
        int oc = oc0 + row;
        size_t o = ((size_t)(b * C_ + oc)) * HW_ + hw0 + cs;
        uint2 xv = *(const uint2*)(xPb + o);
        f32x4 ov;
        ov[0] = g * bf2f((unsigned short)(tv.x & 0xFFFF)) + bf2f((unsigned short)(xv.x & 0xFFFF));
        ov[1] = g * bf2f((unsigned short)(tv.x >> 16))    + bf2f((unsigned short)(xv.x >> 16));
        ov[2] = g * bf2f((unsigned short)(tv.y & 0xFFFF)) + bf2f((unsigned short)(xv.y & 0xFFFF));
        ov[3] = g * bf2f((unsigned short)(tv.y >> 16))    + bf2f((unsigned short)(xv.y >> 16));
        *(f32x4*)(outp + o) = ov;
    }
}

extern "C" void kernel_launch(void* const* d_in, const int* in_sizes, int n_in,
                              void* d_out, int out_size, void* d_ws, size_t ws_size,
                              hipStream_t stream) {
    const float* x  = (const float*)d_in[0];
    const float* Wq = (const float*)d_in[1];
    const float* bq = (const float*)d_in[2];
    const float* Wk = (const float*)d_in[3];
    const float* bk = (const float*)d_in[4];
    const float* Wv = (const float*)d_in[5];
    const float* bv = (const float*)d_in[6];
    const float* gm = (const float*)d_in[7];
    float* out = (float*)d_out;
    char* ws = (char*)d_ws;

    // ws (exactly 189,530,112 B)
    unsigned short* xT    = (unsigned short*)(ws + 0);
    unsigned short* xAgg  = (unsigned short*)(ws + 0);           // after k2a done
    unsigned short* xP    = (unsigned short*)(ws + 75497472);    // live k1 -> k9
    unsigned short* Qb    = (unsigned short*)(ws + 150994944);
    unsigned short* att2  = (unsigned short*)(ws + 150994944);   // after k4 done (overlays Qb/Kb)
    unsigned short* Kb    = (unsigned short*)(ws + 169869312);
    unsigned short* Wqk   = (unsigned short*)(ws + 188743680);
    unsigned short* Wvb   = (unsigned short*)(ws + 189005824);
    // d_out scratch (dead before k9 writes out)
    unsigned short* attf  = (unsigned short*)d_out;              // fp16, 28,311,552 B
    unsigned short* xPT   = (unsigned short*)((char*)d_out + 75497472);  // 75,497,472 B

    k0_wconv<<<1536, 256, 0, stream>>>(Wq, Wk, Wv, Wqk, Wvb);
    k1_xT<<<dim3(288, 16, 8), dim3(32, 8, 1), 0, stream>>>(x, xT, xP);
    k2a_qk<<<576, 512, 0, stream>>>(xT, Wqk, bq, bk, Qb, Kb);
    k3_vt<<<4096, 256, 0, stream>>>(xP, xPT);                      // xPT in d_out scratch
    k4_energy<<<dim3(96, 8, 2), 256, 0, stream>>>(Qb, Kb, attf);   // attf in d_out scratch
    k5_softmax<<<18432, 256, 0, stream>>>(attf, att2);             // att2 overlays Qb/Kb (dead)
    k6_agg<0><<<dim3(2, 768), 512, 0, stream>>>(att2, xP, xAgg);   // xAgg overlays xT (dead)
    k6_agg<1><<<dim3(2, 768), 512, 0, stream>>>(att2, xPT, xAgg);  // accumulate H-direction
    k9_proj<<<2304, 256, 0, stream>>>(xAgg, Wvb, bv, xP, gm, out);
}

// Round 13
// 357.175 us; speedup vs baseline: 1.0688x; 1.0192x over previous
//
#include <hip/hip_runtime.h>

// CrissCrossAttention: B=8 C=512 CQ=128 H=W=96
// out = g*(Wv·xAgg + bv) + x, xAgg = attW·x + attH·x (linearity of V-path).
// ws layout (EXACTLY 189,530,112 B — round-1-proven cap):
//  @0          : xT[p][512]bf16 75,497,472 (k1->k2a) THEN xAgg[p][512]bf16 (k6->k9)
//  @75,497,472 : xP[b][c][h][w]bf16 75,497,472 (k1->k9: k6<0> B-tile + k9 epilogue)
//  @150,994,944: Qb[p][128]bf16 18,874,368 (k2a->k4); after k4: att2 bf16[p][192] 28,311,552 (k5->k6)
//  @169,869,312: Kb[p][128]bf16 18,874,368 (k2a->k4)
//  @188,743,680: Wqk bf16[256][512]; @189,005,824: Wvb bf16[512][512]; end 189,530,112
// d_out scratch until k9 (poisoned-ok, fully rewritten):
//  @0          : attf fp16[p][192] 28,311,552 (k4->k5)
//  @75,497,472 : xPT[b][c][w][h]bf16 75,497,472 (k3->k6<1>)

#define B_ 8
#define C_ 512
#define CQ_ 128
#define H_ 96
#define W_ 96
#define HW_ 9216
#define J_ 192

typedef __attribute__((ext_vector_type(8))) short short8;
typedef __attribute__((ext_vector_type(4))) float f32x4;

__device__ __forceinline__ unsigned short f2bf(float f) {
    unsigned u = __float_as_uint(f);
    u += 0x7FFFu + ((u >> 16) & 1u);
    return (unsigned short)(u >> 16);
}
__device__ __forceinline__ float bf2f(unsigned short h) {
    return __uint_as_float((unsigned)h << 16);
}
__device__ __forceinline__ unsigned short f2h(float f) {
    _Float16 h = (_Float16)f;
    return __builtin_bit_cast(unsigned short, h);
}
__device__ __forceinline__ float h2f(unsigned short u) {
    return (float)__builtin_bit_cast(_Float16, u);
}
__device__ __forceinline__ void gl_lds16(const unsigned short* g, void* lds_base) {
    __builtin_amdgcn_global_load_lds((const __attribute__((address_space(1))) void*)g,
                                     (__attribute__((address_space(3))) void*)lds_base,
                                     16, 0, 0);
}

// ---------------- K0: weights fp32 -> bf16 ----------------
__global__ __launch_bounds__(256) void k0_wconv(const float* __restrict__ Wq,
                                                const float* __restrict__ Wk,
                                                const float* __restrict__ Wv,
                                                unsigned short* __restrict__ Wqk,
                                                unsigned short* __restrict__ Wvb) {
    int i = blockIdx.x * 256 + threadIdx.x;
    if (i < 65536)        Wqk[i] = f2bf(Wq[i]);
    else if (i < 131072)  Wqk[i] = f2bf(Wk[i - 65536]);
    else                  Wvb[i - 131072] = f2bf(Wv[i - 131072]);
}

// ---------------- K1: x f32 -> xT[b][hw][c] bf16 AND xP[b][c][hw] bf16 (vectorized) ----------------
// 64(c) x 64(p) tiles; float4 reads, uint2 writes to xP + LDS; uint2 transposed writes to xT.
__global__ __launch_bounds__(256) void k1_xT(const float* __restrict__ x,
                                             unsigned short* __restrict__ xT,
                                             unsigned short* __restrict__ xP) {
    __shared__ alignas(16) unsigned short tl[64][68];    // +4 pad keeps uint2 alignment
    int b = blockIdx.z, c0 = blockIdx.y * 64, p0 = blockIdx.x * 64;
    int t = threadIdx.x;
    #pragma unroll
    for (int pass = 0; pass < 4; ++pass) {
        int m = t + pass * 256;
        int row = m >> 4, f4 = (m & 15) << 2;            // c-row, p-quad
        size_t off = ((size_t)(b * C_ + c0 + row)) * HW_ + p0 + f4;
        f32x4 v = *(const f32x4*)(x + off);
        uint2 o;
        o.x = (unsigned)f2bf(v[0]) | ((unsigned)f2bf(v[1]) << 16);
        o.y = (unsigned)f2bf(v[2]) | ((unsigned)f2bf(v[3]) << 16);
        *(uint2*)(xP + off) = o;
        *(uint2*)(&tl[row][f4]) = o;
    }
    __syncthreads();
    #pragma unroll
    for (int pass = 0; pass < 4; ++pass) {
        int m = t + pass * 256;
        int pr = m >> 4, cq = (m & 15) << 2;             // p-row, c-quad
        uint2 o;
        o.x = (unsigned)tl[cq + 0][pr] | ((unsigned)tl[cq + 1][pr] << 16);
        o.y = (unsigned)tl[cq + 2][pr] | ((unsigned)tl[cq + 3][pr] << 16);
        *(uint2*)(xT + ((size_t)(b * HW_ + p0 + pr)) * C_ + c0 + cq) = o;
    }
}

// ---------------- K3: plane transpose bf16 (vectorized globals): src[b][c][h][w] -> dst[b][c][w][h] ----------------
__global__ __launch_bounds__(256) void k3_vt(const unsigned short* __restrict__ src_,
                                             unsigned short* __restrict__ dst_) {
    __shared__ unsigned short tl[96][97];
    int plane = blockIdx.x;
    const unsigned short* src = src_ + (size_t)plane * HW_;
    unsigned short* dst = dst_ + (size_t)plane * HW_;
    int t = threadIdx.x;
    for (int m = t; m < 1152; m += 256) {                // 1152 = 96 rows x 12 uint4
        int h = m / 12, w8 = (m % 12) * 8;
        uint4 v = *(const uint4*)(src + h * 96 + w8);
        tl[h][w8 + 0] = (unsigned short)(v.x);
        tl[h][w8 + 1] = (unsigned short)(v.x >> 16);
        tl[h][w8 + 2] = (unsigned short)(v.y);
        tl[h][w8 + 3] = (unsigned short)(v.y >> 16);
        tl[h][w8 + 4] = (unsigned short)(v.z);
        tl[h][w8 + 5] = (unsigned short)(v.z >> 16);
        tl[h][w8 + 6] = (unsigned short)(v.w);
        tl[h][w8 + 7] = (unsigned short)(v.w >> 16);
    }
    __syncthreads();
    for (int m = t; m < 1152; m += 256) {
        int w = m / 12, h8 = (m % 12) * 8;
        uint4 o;
        o.x = (unsigned)tl[h8 + 0][w] | ((unsigned)tl[h8 + 1][w] << 16);
        o.y = (unsigned)tl[h8 + 2][w] | ((unsigned)tl[h8 + 3][w] << 16);
        o.z = (unsigned)tl[h8 + 4][w] | ((unsigned)tl[h8 + 5][w] << 16);
        o.w = (unsigned)tl[h8 + 6][w] | ((unsigned)tl[h8 + 7][w] << 16);
        *(uint4*)(dst + w * 96 + h8) = o;
    }
}

// ---------------- K2a: Q,K projection, BK=32 dbuf counted-vmcnt (round-8-verified pattern) ----------------
// BM=128(p) BN=256(oc), 8 waves (2p x 4oc of 64x64), LDS 48KB -> 3 blocks/CU.
__global__ __launch_bounds__(512) void k2a_qk(const unsigned short* __restrict__ xT,
                                              const unsigned short* __restrict__ Wqk,
                                              const float* __restrict__ bq,
                                              const float* __restrict__ bk,
                                              unsigned short* __restrict__ Qb,
                                              unsigned short* __restrict__ Kb) {
    __shared__ alignas(16) char smem[49152];
    unsigned short* AsBase = (unsigned short*)smem;            // [2][128][32] = 16 KB
    unsigned short* BsBase = (unsigned short*)(smem + 16384);  // [2][256][32] = 32 KB
    int t = threadIdx.x;
    int p0 = blockIdx.x * 128;
    int wid = t >> 6, lane = t & 63;
    int wr = wid >> 2, wc = wid & 3;                 // 2(p:64) x 4(oc:64)
    int srow = lane >> 2;                            // chunk: 16 rows x 32 cols = 1KB
    int sk8 = (((lane & 3) ^ (srow & 3)) << 3);      // XOR swizzle within 4 col-groups
    const f32x4 zero = {0.f, 0.f, 0.f, 0.f};
    f32x4 acc[4][4];
    for (int m = 0; m < 4; ++m) for (int n = 0; n < 4; ++n) acc[m][n] = zero;

    // stage one BK=32 tile pair: A 8 chunks (1/wave) + B 16 chunks (2/wave) = 3 gl_lds/wave
    auto STAGE = [&](int buf, int ks) {
        {
            int q = wid; int row = q * 16 + srow;
            gl_lds16(xT + ((size_t)(p0 + row) << 9) + ks + sk8,
                     smem + buf * 8192 + q * 1024);
        }
        #pragma unroll
        for (int i = 0; i < 2; ++i) {
            int q = wid * 2 + i; int row = q * 16 + srow;
            gl_lds16(Wqk + ((size_t)row << 9) + ks + sk8,
                     smem + 16384 + buf * 16384 + q * 1024);
        }
    };

    STAGE(0, 0);
    #pragma unroll
    for (int step = 0; step < 16; ++step) {
        int cur = step & 1;
        if (step < 15) {
            STAGE(cur ^ 1, (step + 1) * 32);             // prefetch next tile
            asm volatile("s_waitcnt vmcnt(3)" ::: "memory");   // cur's 3 loads done; next in flight
        } else {
            asm volatile("s_waitcnt vmcnt(0)" ::: "memory");
        }
        __builtin_amdgcn_s_barrier();
        __builtin_amdgcn_sched_barrier(0);
        {
            short8 af[4], bfv[4];
            #pragma unroll
            for (int m = 0; m < 4; ++m) {
                int row = wr * 64 + m * 16 + (lane & 15);
                int po = (((lane >> 4) ^ (row & 3)) << 3);
                af[m] = *(const short8*)(AsBase + cur * 4096 + row * 32 + po);
            }
            #pragma unroll
            for (int n = 0; n < 4; ++n) {
                int row = wc * 64 + n * 16 + (lane & 15);
                int po = (((lane >> 4) ^ (row & 3)) << 3);
                bfv[n] = *(const short8*)(BsBase + cur * 8192 + row * 32 + po);
            }
            #pragma unroll
            for (int m = 0; m < 4; ++m)
                #pragma unroll
                for (int n = 0; n < 4; ++n)
                    acc[m][n] = __builtin_amdgcn_mfma_f32_16x16x32_bf16(af[m], bfv[n], acc[m][n], 0, 0, 0);
        }
        __builtin_amdgcn_s_barrier();
    }
    #pragma unroll
    for (int n = 0; n < 4; ++n) {
        int oc = wc * 64 + n * 16 + (lane & 15);
        float bias = (oc < 128) ? bq[oc] : bk[oc - 128];
        unsigned short* dst = (oc < 128) ? (Qb + oc) : (Kb + (oc - 128));
        #pragma unroll
        for (int m = 0; m < 4; ++m) {
            int pr = p0 + wr * 64 + m * 16 + ((lane >> 4) << 2);
            #pragma unroll
            for (int r = 0; r < 4; ++r)
                dst[(size_t)(pr + r) << 7] = f2bf(acc[m][n][r] + bias);
        }
    }
}

// ---------------- K4: energies (fp16 out). z=0: E_W; z=1: E_H (diag=-inf) ----------------
__global__ __launch_bounds__(256) void k4_energy(const unsigned short* __restrict__ Qb,
                                                 const unsigned short* __restrict__ Kb,
                                                 unsigned short* __restrict__ att) {
    __shared__ alignas(16) unsigned short Qs[96][136];
    __shared__ alignas(16) unsigned short Ks[96][136];
    int t = threadIdx.x;
    int modeH = blockIdx.z;
    int b = blockIdx.y, v0 = blockIdx.x;
    size_t base, rstride, obase_off, ostride;
    if (!modeH) {
        base      = (size_t)((b * H_ + v0) * W_) * CQ_;
        rstride   = CQ_;
        obase_off = (size_t)((b * H_ + v0) * W_) * J_ + H_;
        ostride   = J_;
    } else {
        base      = ((size_t)(b * H_) * W_ + v0) * CQ_;
        rstride   = (size_t)W_ * CQ_;
        obase_off = ((size_t)(b * H_) * W_ + v0) * J_;
        ostride   = (size_t)W_ * J_;
    }
    for (int q = t; q < 1536; q += 256) {
        int row = q >> 4, c8 = (q & 15) << 3;
        *(uint4*)(&Qs[row][c8]) = *(const uint4*)(Qb + base + (size_t)row * rstride + c8);
        *(uint4*)(&Ks[row][c8]) = *(const uint4*)(Kb + base + (size_t)row * rstride + c8);
    }
    __syncthreads();
    int wid = t >> 6, lane = t & 63;
    int wr = wid >> 1, wc = wid & 1;
    const f32x4 zero = {0.f, 0.f, 0.f, 0.f};
    f32x4 acc[3][3];
    for (int m = 0; m < 3; ++m) for (int n = 0; n < 3; ++n) acc[m][n] = zero;
    #pragma unroll
    for (int ks = 0; ks < 128; ks += 32) {
        int ko = ks + ((lane >> 4) << 3);
        short8 af[3], bfv[3];
        #pragma unroll
        for (int m = 0; m < 3; ++m) af[m] = *(const short8*)(&Qs[wr * 48 + m * 16 + (lane & 15)][ko]);
        #pragma unroll
        for (int n = 0; n < 3; ++n) bfv[n] = *(const short8*)(&Ks[wc * 48 + n * 16 + (lane & 15)][ko]);
        #pragma unroll
        for (int m = 0; m < 3; ++m)
            #pragma unroll
            for (int n = 0; n < 3; ++n)
                acc[m][n] = __builtin_amdgcn_mfma_f32_16x16x32_bf16(af[m], bfv[n], acc[m][n], 0, 0, 0);
    }
    unsigned short* ob = att + obase_off;
    #pragma unroll
    for (int m = 0; m < 3; ++m) {
        int i = wr * 48 + m * 16 + ((lane >> 4) << 2);
        #pragma unroll
        for (int n = 0; n < 3; ++n) {
            int j = wc * 48 + n * 16 + (lane & 15);
            #pragma unroll
            for (int r = 0; r < 4; ++r) {
                float v = acc[m][n][r];
                if (modeH && (i + r) == j) v = -__builtin_inff();
                ob[(size_t)(i + r) * ostride + j] = f2h(v);
            }
        }
    }
}

// ---------------- K5: softmax over 192 (fp16 in) -> bf16 att2 ----------------
__global__ __launch_bounds__(256) void k5_softmax(const unsigned short* __restrict__ att,
                                                  unsigned short* __restrict__ att2) {
    int r = blockIdx.x * 4 + (threadIdx.x >> 6);
    int lane = threadIdx.x & 63;
    const unsigned short* row = att + (size_t)r * J_;
    float e0 = h2f(row[lane]), e1 = h2f(row[lane + 64]), e2 = h2f(row[lane + 128]);
    float m = fmaxf(e0, fmaxf(e1, e2));
    #pragma unroll
    for (int off = 32; off; off >>= 1) m = fmaxf(m, __shfl_xor(m, off, 64));
    float p0 = __expf(e0 - m), p1 = __expf(e1 - m), p2 = __expf(e2 - m);
    float s = p0 + p1 + p2;
    #pragma unroll
    for (int off = 32; off; off >>= 1) s += __shfl_xor(s, off, 64);
    float inv = 1.f / s;
    unsigned short* orow = att2 + (size_t)r * J_;
    orow[lane]       = f2bf(p0 * inv);
    orow[lane + 64]  = f2bf(p1 * inv);
    orow[lane + 128] = f2bf(p2 * inv);
}

// ---------------- K6: x-aggregation. D[row][c] = sum_j A[row][j] * Xsrc[c][v*96+j] ----------------
// MODE 0 (W-dir): per (b, h=v): A=attW rows w; Xsrc=xP.   D[w][c] -> xAgg (overwrite)
// MODE 1 (H-dir): per (b, w=v): A=attH rows h; Xsrc=xPT.  D[h][c] -> xAgg (+= accumulate)
template <int MODE>
__global__ __launch_bounds__(512) void k6_agg(const unsigned short* __restrict__ att2,
                                              const unsigned short* __restrict__ Xsrc,
                                              unsigned short* __restrict__ xAgg) {
    __shared__ alignas(16) unsigned short As[96][104];
    __shared__ alignas(16) unsigned short Bs[256][104];
    int t = threadIdx.x;
    int c0 = blockIdx.x * 256;
    int b = blockIdx.y / 96;
    int v = blockIdx.y % 96;
    size_t abase, astride;
    if (MODE == 0) { abase = ((size_t)(b * HW_) + (size_t)v * 96) * J_ + 96; astride = J_; }
    else           { abase = (size_t)(b * HW_) * J_ + (size_t)v * J_;        astride = (size_t)96 * J_; }
    if (t < 192) {
        int row = t >> 1, cs = (t & 1) * 6;
        const unsigned short* src = att2 + abase + (size_t)row * astride;
        #pragma unroll
        for (int i = 0; i < 6; ++i)
            *(uint4*)(&As[row][(cs + i) * 8]) = *(const uint4*)(src + (cs + i) * 8);
    }
    {
        int row = t >> 1, cs = (t & 1) * 6;
        const unsigned short* src = Xsrc + ((size_t)(b * C_) + c0 + row) * HW_ + v * 96;
        #pragma unroll
        for (int i = 0; i < 6; ++i)
            *(uint4*)(&Bs[row][(cs + i) * 8]) = *(const uint4*)(src + (cs + i) * 8);
    }
    __syncthreads();
    int wid = t >> 6, lane = t & 63;
    int wr = wid >> 2, wc = wid & 3;                 // 2(m:48) x 4(n:64)
    const f32x4 zero = {0.f, 0.f, 0.f, 0.f};
    f32x4 acc[3][4];
    for (int m = 0; m < 3; ++m) for (int n = 0; n < 4; ++n) acc[m][n] = zero;
    #pragma unroll
    for (int ks = 0; ks < 96; ks += 32) {
        int ko = ks + ((lane >> 4) << 3);
        short8 af[3], bfv[4];
        #pragma unroll
        for (int m = 0; m < 3; ++m) af[m] = *(const short8*)(&As[wr * 48 + m * 16 + (lane & 15)][ko]);
        #pragma unroll
        for (int n = 0; n < 4; ++n) bfv[n] = *(const short8*)(&Bs[wc * 64 + n * 16 + (lane & 15)][ko]);
        #pragma unroll
        for (int m = 0; m < 3; ++m)
            #pragma unroll
            for (int n = 0; n < 4; ++n)
                acc[m][n] = __builtin_amdgcn_mfma_f32_16x16x32_bf16(af[m], bfv[n], acc[m][n], 0, 0, 0);
    }
    #pragma unroll
    for (int m = 0; m < 3; ++m) {
        int orow = wr * 48 + m * 16 + ((lane >> 4) << 2);
        #pragma unroll
        for (int n = 0; n < 4; ++n) {
            int c = c0 + wc * 64 + n * 16 + (lane & 15);
            #pragma unroll
            for (int r = 0; r < 4; ++r) {
                int p = (MODE == 0) ? (v * 96 + orow + r) : ((orow + r) * 96 + v);
                size_t o = ((size_t)(b * HW_) + p) * C_ + c;
                if (MODE == 0) xAgg[o] = f2bf(acc[m][n][r]);
                else           xAgg[o] = f2bf(bf2f(xAgg[o]) + acc[m][n][r]);
            }
        }
    }
}

// ---------------- K9: fused projection + epilogue, BK=32 dbuf counted-vmcnt + LDS-bounce epilogue ----------------
// (round-10 proven config: 95.6 us)
// D[oc][p] = sum_k Wv[oc][k]*xAgg[p][k]; out[b][oc][p] = g*(D+bv[oc]) + bf2f(xP[b][oc][p])
// BM=128(oc) BN=128(p) BK=32 dbuf, 4 waves (2x2 of 64x64), LDS 32KB -> 5 blocks/CU.
__global__ __launch_bounds__(256) void k9_proj(const unsigned short* __restrict__ xAgg,
                                               const unsigned short* __restrict__ Wvb,
                                               const float* __restrict__ bv,
                                               const unsigned short* __restrict__ xPb,
                                               const float* __restrict__ gamma_p,
                                               float* __restrict__ outp) {
    __shared__ alignas(16) char smem[32768];
    unsigned short* AsBase = (unsigned short*)smem;            // [2][128][32] = 16 KB
    unsigned short* BsBase = (unsigned short*)(smem + 16384);  // [2][128][32] = 16 KB
    int t = threadIdx.x;
    int bid = blockIdx.x;
    int tile = (bid & 7) * 288 + (bid >> 3);             // XCD-chunked remap (2304 = 8*288)
    int oc0 = (tile & 3) * 128;
    int pt  = tile >> 2;                                 // 0..575
    int p0  = pt * 128;
    int wid = t >> 6, lane = t & 63;
    int wr = wid >> 1, wc = wid & 1;                     // 2(oc:64) x 2(p:64)
    int srow = lane >> 2;                                // chunk: 16 rows x 32 cols = 1KB
    int sk8 = (((lane & 3) ^ (srow & 3)) << 3);          // XOR swizzle within 4 col-groups
    const f32x4 zero = {0.f, 0.f, 0.f, 0.f};
    f32x4 acc[4][4];
    for (int m = 0; m < 4; ++m) for (int n = 0; n < 4; ++n) acc[m][n] = zero;

    auto STAGE = [&](int buf, int ks) {
        #pragma unroll
        for (int i = 0; i < 2; ++i) {
            int q = wid * 2 + i; int row = q * 16 + srow;
            gl_lds16(Wvb + ((size_t)(oc0 + row) << 9) + ks + sk8,
                     smem + buf * 8192 + q * 1024);
        }
        #pragma unroll
        for (int i = 0; i < 2; ++i) {
            int q = wid * 2 + i; int row = q * 16 + srow;
            gl_lds16(xAgg + ((size_t)(p0 + row) << 9) + ks + sk8,
                     smem + 16384 + buf * 8192 + q * 1024);
        }
    };

    STAGE(0, 0);
    #pragma unroll
    for (int step = 0; step < 16; ++step) {
        int cur = step & 1;
        if (step < 15) {
            STAGE(cur ^ 1, (step + 1) * 32);             // prefetch next tile
            asm volatile("s_waitcnt vmcnt(4)" ::: "memory");   // cur's 4 loads done
        } else {
            asm volatile("s_waitcnt vmcnt(0)" ::: "memory");
        }
        __builtin_amdgcn_s_barrier();
        __builtin_amdgcn_sched_barrier(0);
        {
            short8 af[4], bfv[4];
            #pragma unroll
            for (int m = 0; m < 4; ++m) {
                int row = wr * 64 + m * 16 + (lane & 15);
                int po = (((lane >> 4) ^ (row & 3)) << 3);
                af[m] = *(const short8*)(AsBase + cur * 4096 + row * 32 + po);
            }
            #pragma unroll
            for (int n = 0; n < 4; ++n) {
                int row = wc * 64 + n * 16 + (lane & 15);
                int po = (((lane >> 4) ^ (row & 3)) << 3);
                bfv[n] = *(const short8*)(BsBase + cur * 4096 + row * 32 + po);
            }
            #pragma unroll
            for (int m = 0; m < 4; ++m)
                #pragma unroll
                for (int n = 0; n < 4; ++n)
                    acc[m][n] = __builtin_amdgcn_mfma_f32_16x16x32_bf16(af[m], bfv[n], acc[m][n], 0, 0, 0);
        }
        __builtin_amdgcn_s_barrier();
    }
    __syncthreads();                                     // staging LDS now dead; safe to reuse

    // Phase 1: acc + bias -> bf16 tile [128 rows][128 cols], 16B-granule XOR swizzle
    #pragma unroll
    for (int m = 0; m < 4; ++m) {
        int rowb = wr * 64 + m * 16 + ((lane >> 4) << 2);
        #pragma unroll
        for (int r = 0; r < 4; ++r) {
            int row = rowb + r;
            float bias = bv[oc0 + row];
            #pragma unroll
            for (int n = 0; n < 4; ++n) {
                int col = wc * 64 + n * 16 + (lane & 15);
                int baddr = row * 256 + ((col << 1) ^ ((row & 7) << 4));
                *(unsigned short*)(smem + baddr) = f2bf(acc[m][n][r] + bias);
            }
        }
    }
    __syncthreads();

    // Phase 2: coalesced write-out. 16 passes x (8 rows x 128 cols).
    int b = pt / 72;
    int hw0 = (pt % 72) * 128;
    float g = gamma_p[0];
    #pragma unroll
    for (int pass = 0; pass < 16; ++pass) {
        int row = pass * 8 + (t >> 5);
        int cs = (t & 31) * 4;
        uint2 tv = *(const uint2*)(smem + row * 256 + ((cs << 1) ^ ((row & 7) << 4)));
        int oc = oc0 + row;
        size_t o = ((size_t)(b * C_ + oc)) * HW_ + hw0 + cs;
        uint2 xv = *(const uint2*)(xPb + o);
        f32x4 ov;
        ov[0] = g * bf2f((unsigned short)(tv.x & 0xFFFF)) + bf2f((unsigned short)(xv.x & 0xFFFF));
        ov[1] = g * bf2f((unsigned short)(tv.x >> 16))    + bf2f((unsigned short)(xv.x >> 16));
        ov[2] = g * bf2f((unsigned short)(tv.y & 0xFFFF)) + bf2f((unsigned short)(xv.y & 0xFFFF));
        ov[3] = g * bf2f((unsigned short)(tv.y >> 16))    + bf2f((unsigned short)(xv.y >> 16));
        *(f32x4*)(outp + o) = ov;
    }
}

extern "C" void kernel_launch(void* const* d_in, const int* in_sizes, int n_in,
                              void* d_out, int out_size, void* d_ws, size_t ws_size,
                              hipStream_t stream) {
    const float* x  = (const float*)d_in[0];
    const float* Wq = (const float*)d_in[1];
    const float* bq = (const float*)d_in[2];
    const float* Wk = (const float*)d_in[3];
    const float* bk = (const float*)d_in[4];
    const float* Wv = (const float*)d_in[5];
    const float* bv = (const float*)d_in[6];
    const float* gm = (const float*)d_in[7];
    float* out = (float*)d_out;
    char* ws = (char*)d_ws;

    // ws (exactly 189,530,112 B)
    unsigned short* xT    = (unsigned short*)(ws + 0);
    unsigned short* xAgg  = (unsigned short*)(ws + 0);           // after k2a done
    unsigned short* xP    = (unsigned short*)(ws + 75497472);    // live k1 -> k9
    unsigned short* Qb    = (unsigned short*)(ws + 150994944);
    unsigned short* att2  = (unsigned short*)(ws + 150994944);   // after k4 done (overlays Qb/Kb)
    unsigned short* Kb    = (unsigned short*)(ws + 169869312);
    unsigned short* Wqk   = (unsigned short*)(ws + 188743680);
    unsigned short* Wvb   = (unsigned short*)(ws + 189005824);
    // d_out scratch (dead before k9 writes out)
    unsigned short* attf  = (unsigned short*)d_out;              // fp16, 28,311,552 B
    unsigned short* xPT   = (unsigned short*)((char*)d_out + 75497472);  // 75,497,472 B

    k0_wconv<<<1536, 256, 0, stream>>>(Wq, Wk, Wv, Wqk, Wvb);
    k1_xT<<<dim3(144, 8, 8), 256, 0, stream>>>(x, xT, xP);
    k2a_qk<<<576, 512, 0, stream>>>(xT, Wqk, bq, bk, Qb, Kb);
    k3_vt<<<4096, 256, 0, stream>>>(xP, xPT);                      // xPT in d_out scratch
    k4_energy<<<dim3(96, 8, 2), 256, 0, stream>>>(Qb, Kb, attf);   // attf in d_out scratch
    k5_softmax<<<18432, 256, 0, stream>>>(attf, att2);             // att2 overlays Qb/Kb (dead)
    k6_agg<0><<<dim3(2, 768), 512, 0, stream>>>(att2, xP, xAgg);   // xAgg overlays xT (dead)
    k6_agg<1><<<dim3(2, 768), 512, 0, stream>>>(att2, xPT, xAgg);  // accumulate H-direction
    k9_proj<<<2304, 256, 0, stream>>>(xAgg, Wvb, bv, xP, gm, out);
}

// Round 14
// 341.543 us; speedup vs baseline: 1.1177x; 1.0458x over previous
//
#include <hip/hip_runtime.h>

// CrissCrossAttention: B=8 C=512 CQ=128 H=W=96
// out = g*(Wv·xAgg + bv) + x, xAgg = attW·x + attH·x (linearity of V-path).
// ROUND 14: k9 GEMM operands in fp8 e4m3 (Wv pre-scaled x16, epilogue /16). xAgg stored fp8.
// ws layout:
//  @0          : xT[p][512]bf16 75,497,472 (k1->k2a) THEN xAgg8[p][512]fp8 37,748,736 (k6->k9)
//  @75,497,472 : xP[b][c][h][w]bf16 75,497,472 (k1->k9)
//  @150,994,944: Qb[p][128]bf16 (k2a->k4); after k4: att2 bf16[p][192] (k5->k6)
//  @169,869,312: Kb[p][128]bf16 (k2a->k4)
//  @188,743,680: Wqk bf16[256][512]; @189,005,824: Wv8 fp8[512][512] (262,144 B)
// d_out scratch until k9: attf fp16 @0; xPT bf16 @75,497,472

#define B_ 8
#define C_ 512
#define CQ_ 128
#define H_ 96
#define W_ 96
#define HW_ 9216
#define J_ 192

typedef __attribute__((ext_vector_type(8))) short short8;
typedef __attribute__((ext_vector_type(4))) float f32x4;

__device__ __forceinline__ unsigned short f2bf(float f) {
    unsigned u = __float_as_uint(f);
    u += 0x7FFFu + ((u >> 16) & 1u);
    return (unsigned short)(u >> 16);
}
__device__ __forceinline__ float bf2f(unsigned short h) {
    return __uint_as_float((unsigned)h << 16);
}
__device__ __forceinline__ unsigned short f2h(float f) {
    _Float16 h = (_Float16)f;
    return __builtin_bit_cast(unsigned short, h);
}
__device__ __forceinline__ float h2f(unsigned short u) {
    return (float)__builtin_bit_cast(_Float16, u);
}
__device__ __forceinline__ unsigned char f2fp8(float v) {
    return (unsigned char)(__builtin_amdgcn_cvt_pk_fp8_f32(v, 0.f, 0, 0) & 0xFF);
}
__device__ __forceinline__ float fp82f(unsigned char v) {
    return __builtin_amdgcn_cvt_f32_fp8((int)v, 0);
}
__device__ __forceinline__ void gl_lds16(const void* g, void* lds_base) {
    __builtin_amdgcn_global_load_lds((const __attribute__((address_space(1))) void*)g,
                                     (__attribute__((address_space(3))) void*)lds_base,
                                     16, 0, 0);
}

// ---------------- K0: weights -> bf16 (Wqk) and fp8 x16 (Wv) ----------------
__global__ __launch_bounds__(256) void k0_wconv(const float* __restrict__ Wq,
                                                const float* __restrict__ Wk,
                                                const float* __restrict__ Wv,
                                                unsigned short* __restrict__ Wqk,
                                                unsigned* __restrict__ Wv8u) {
    int i = blockIdx.x * 256 + threadIdx.x;          // grid 768*256 = 196608
    if (i < 65536)        Wqk[i] = f2bf(Wq[i]);
    else if (i < 131072)  Wqk[i] = f2bf(Wk[i - 65536]);
    else {
        int j = (i - 131072) * 4;                    // 4 fp8 per thread
        int u = __builtin_amdgcn_cvt_pk_fp8_f32(Wv[j] * 16.f, Wv[j + 1] * 16.f, 0, 0);
        u = __builtin_amdgcn_cvt_pk_fp8_f32(Wv[j + 2] * 16.f, Wv[j + 3] * 16.f, u, 1);
        Wv8u[i - 131072] = (unsigned)u;
    }
}

// ---------------- K1: x f32 -> xT[b][hw][c] bf16 AND xP[b][c][hw] bf16 (vectorized) ----------------
__global__ __launch_bounds__(256) void k1_xT(const float* __restrict__ x,
                                             unsigned short* __restrict__ xT,
                                             unsigned short* __restrict__ xP) {
    __shared__ alignas(16) unsigned short tl[64][68];
    int b = blockIdx.z, c0 = blockIdx.y * 64, p0 = blockIdx.x * 64;
    int t = threadIdx.x;
    #pragma unroll
    for (int pass = 0; pass < 4; ++pass) {
        int m = t + pass * 256;
        int row = m >> 4, f4 = (m & 15) << 2;
        size_t off = ((size_t)(b * C_ + c0 + row)) * HW_ + p0 + f4;
        f32x4 v = *(const f32x4*)(x + off);
        uint2 o;
        o.x = (unsigned)f2bf(v[0]) | ((unsigned)f2bf(v[1]) << 16);
        o.y = (unsigned)f2bf(v[2]) | ((unsigned)f2bf(v[3]) << 16);
        *(uint2*)(xP + off) = o;
        *(uint2*)(&tl[row][f4]) = o;
    }
    __syncthreads();
    #pragma unroll
    for (int pass = 0; pass < 4; ++pass) {
        int m = t + pass * 256;
        int pr = m >> 4, cq = (m & 15) << 2;
        uint2 o;
        o.x = (unsigned)tl[cq + 0][pr] | ((unsigned)tl[cq + 1][pr] << 16);
        o.y = (unsigned)tl[cq + 2][pr] | ((unsigned)tl[cq + 3][pr] << 16);
        *(uint2*)(xT + ((size_t)(b * HW_ + p0 + pr)) * C_ + c0 + cq) = o;
    }
}

// ---------------- K3: plane transpose bf16 (vectorized globals) ----------------
__global__ __launch_bounds__(256) void k3_vt(const unsigned short* __restrict__ src_,
                                             unsigned short* __restrict__ dst_) {
    __shared__ unsigned short tl[96][97];
    int plane = blockIdx.x;
    const unsigned short* src = src_ + (size_t)plane * HW_;
    unsigned short* dst = dst_ + (size_t)plane * HW_;
    int t = threadIdx.x;
    for (int m = t; m < 1152; m += 256) {
        int h = m / 12, w8 = (m % 12) * 8;
        uint4 v = *(const uint4*)(src + h * 96 + w8);
        tl[h][w8 + 0] = (unsigned short)(v.x);
        tl[h][w8 + 1] = (unsigned short)(v.x >> 16);
        tl[h][w8 + 2] = (unsigned short)(v.y);
        tl[h][w8 + 3] = (unsigned short)(v.y >> 16);
        tl[h][w8 + 4] = (unsigned short)(v.z);
        tl[h][w8 + 5] = (unsigned short)(v.z >> 16);
        tl[h][w8 + 6] = (unsigned short)(v.w);
        tl[h][w8 + 7] = (unsigned short)(v.w >> 16);
    }
    __syncthreads();
    for (int m = t; m < 1152; m += 256) {
        int w = m / 12, h8 = (m % 12) * 8;
        uint4 o;
        o.x = (unsigned)tl[h8 + 0][w] | ((unsigned)tl[h8 + 1][w] << 16);
        o.y = (unsigned)tl[h8 + 2][w] | ((unsigned)tl[h8 + 3][w] << 16);
        o.z = (unsigned)tl[h8 + 4][w] | ((unsigned)tl[h8 + 5][w] << 16);
        o.w = (unsigned)tl[h8 + 6][w] | ((unsigned)tl[h8 + 7][w] << 16);
        *(uint4*)(dst + w * 96 + h8) = o;
    }
}

// ---------------- K2a: Q,K projection, BK=32 dbuf counted-vmcnt ----------------
__global__ __launch_bounds__(512) void k2a_qk(const unsigned short* __restrict__ xT,
                                              const unsigned short* __restrict__ Wqk,
                                              const float* __restrict__ bq,
                                              const float* __restrict__ bk,
                                              unsigned short* __restrict__ Qb,
                                              unsigned short* __restrict__ Kb) {
    __shared__ alignas(16) char smem[49152];
    unsigned short* AsBase = (unsigned short*)smem;            // [2][128][32] = 16 KB
    unsigned short* BsBase = (unsigned short*)(smem + 16384);  // [2][256][32] = 32 KB
    int t = threadIdx.x;
    int p0 = blockIdx.x * 128;
    int wid = t >> 6, lane = t & 63;
    int wr = wid >> 2, wc = wid & 3;
    int srow = lane >> 2;
    int sk8 = (((lane & 3) ^ (srow & 3)) << 3);
    const f32x4 zero = {0.f, 0.f, 0.f, 0.f};
    f32x4 acc[4][4];
    for (int m = 0; m < 4; ++m) for (int n = 0; n < 4; ++n) acc[m][n] = zero;

    auto STAGE = [&](int buf, int ks) {
        {
            int q = wid; int row = q * 16 + srow;
            gl_lds16(xT + ((size_t)(p0 + row) << 9) + ks + sk8,
                     smem + buf * 8192 + q * 1024);
        }
        #pragma unroll
        for (int i = 0; i < 2; ++i) {
            int q = wid * 2 + i; int row = q * 16 + srow;
            gl_lds16(Wqk + ((size_t)row << 9) + ks + sk8,
                     smem + 16384 + buf * 16384 + q * 1024);
        }
    };

    STAGE(0, 0);
    #pragma unroll
    for (int step = 0; step < 16; ++step) {
        int cur = step & 1;
        if (step < 15) {
            STAGE(cur ^ 1, (step + 1) * 32);
            asm volatile("s_waitcnt vmcnt(3)" ::: "memory");
        } else {
            asm volatile("s_waitcnt vmcnt(0)" ::: "memory");
        }
        __builtin_amdgcn_s_barrier();
        __builtin_amdgcn_sched_barrier(0);
        {
            short8 af[4], bfv[4];
            #pragma unroll
            for (int m = 0; m < 4; ++m) {
                int row = wr * 64 + m * 16 + (lane & 15);
                int po = (((lane >> 4) ^ (row & 3)) << 3);
                af[m] = *(const short8*)(AsBase + cur * 4096 + row * 32 + po);
            }
            #pragma unroll
            for (int n = 0; n < 4; ++n) {
                int row = wc * 64 + n * 16 + (lane & 15);
                int po = (((lane >> 4) ^ (row & 3)) << 3);
                bfv[n] = *(const short8*)(BsBase + cur * 8192 + row * 32 + po);
            }
            #pragma unroll
            for (int m = 0; m < 4; ++m)
                #pragma unroll
                for (int n = 0; n < 4; ++n)
                    acc[m][n] = __builtin_amdgcn_mfma_f32_16x16x32_bf16(af[m], bfv[n], acc[m][n], 0, 0, 0);
        }
        __builtin_amdgcn_s_barrier();
    }
    #pragma unroll
    for (int n = 0; n < 4; ++n) {
        int oc = wc * 64 + n * 16 + (lane & 15);
        float bias = (oc < 128) ? bq[oc] : bk[oc - 128];
        unsigned short* dst = (oc < 128) ? (Qb + oc) : (Kb + (oc - 128));
        #pragma unroll
        for (int m = 0; m < 4; ++m) {
            int pr = p0 + wr * 64 + m * 16 + ((lane >> 4) << 2);
            #pragma unroll
            for (int r = 0; r < 4; ++r)
                dst[(size_t)(pr + r) << 7] = f2bf(acc[m][n][r] + bias);
        }
    }
}

// ---------------- K4: energies (fp16 out). z=0: E_W; z=1: E_H (diag=-inf) ----------------
__global__ __launch_bounds__(256) void k4_energy(const unsigned short* __restrict__ Qb,
                                                 const unsigned short* __restrict__ Kb,
                                                 unsigned short* __restrict__ att) {
    __shared__ alignas(16) unsigned short Qs[96][136];
    __shared__ alignas(16) unsigned short Ks[96][136];
    int t = threadIdx.x;
    int modeH = blockIdx.z;
    int b = blockIdx.y, v0 = blockIdx.x;
    size_t base, rstride, obase_off, ostride;
    if (!modeH) {
        base      = (size_t)((b * H_ + v0) * W_) * CQ_;
        rstride   = CQ_;
        obase_off = (size_t)((b * H_ + v0) * W_) * J_ + H_;
        ostride   = J_;
    } else {
        base      = ((size_t)(b * H_) * W_ + v0) * CQ_;
        rstride   = (size_t)W_ * CQ_;
        obase_off = ((size_t)(b * H_) * W_ + v0) * J_;
        ostride   = (size_t)W_ * J_;
    }
    for (int q = t; q < 1536; q += 256) {
        int row = q >> 4, c8 = (q & 15) << 3;
        *(uint4*)(&Qs[row][c8]) = *(const uint4*)(Qb + base + (size_t)row * rstride + c8);
        *(uint4*)(&Ks[row][c8]) = *(const uint4*)(Kb + base + (size_t)row * rstride + c8);
    }
    __syncthreads();
    int wid = t >> 6, lane = t & 63;
    int wr = wid >> 1, wc = wid & 1;
    const f32x4 zero = {0.f, 0.f, 0.f, 0.f};
    f32x4 acc[3][3];
    for (int m = 0; m < 3; ++m) for (int n = 0; n < 3; ++n) acc[m][n] = zero;
    #pragma unroll
    for (int ks = 0; ks < 128; ks += 32) {
        int ko = ks + ((lane >> 4) << 3);
        short8 af[3], bfv[3];
        #pragma unroll
        for (int m = 0; m < 3; ++m) af[m] = *(const short8*)(&Qs[wr * 48 + m * 16 + (lane & 15)][ko]);
        #pragma unroll
        for (int n = 0; n < 3; ++n) bfv[n] = *(const short8*)(&Ks[wc * 48 + n * 16 + (lane & 15)][ko]);
        #pragma unroll
        for (int m = 0; m < 3; ++m)
            #pragma unroll
            for (int n = 0; n < 3; ++n)
                acc[m][n] = __builtin_amdgcn_mfma_f32_16x16x32_bf16(af[m], bfv[n], acc[m][n], 0, 0, 0);
    }
    unsigned short* ob = att + obase_off;
    #pragma unroll
    for (int m = 0; m < 3; ++m) {
        int i = wr * 48 + m * 16 + ((lane >> 4) << 2);
        #pragma unroll
        for (int n = 0; n < 3; ++n) {
            int j = wc * 48 + n * 16 + (lane & 15);
            #pragma unroll
            for (int r = 0; r < 4; ++r) {
                float v = acc[m][n][r];
                if (modeH && (i + r) == j) v = -__builtin_inff();
                ob[(size_t)(i + r) * ostride + j] = f2h(v);
            }
        }
    }
}

// ---------------- K5: softmax over 192 (fp16 in) -> bf16 att2 ----------------
__global__ __launch_bounds__(256) void k5_softmax(const unsigned short* __restrict__ att,
                                                  unsigned short* __restrict__ att2) {
    int r = blockIdx.x * 4 + (threadIdx.x >> 6);
    int lane = threadIdx.x & 63;
    const unsigned short* row = att + (size_t)r * J_;
    float e0 = h2f(row[lane]), e1 = h2f(row[lane + 64]), e2 = h2f(row[lane + 128]);
    float m = fmaxf(e0, fmaxf(e1, e2));
    #pragma unroll
    for (int off = 32; off; off >>= 1) m = fmaxf(m, __shfl_xor(m, off, 64));
    float p0 = __expf(e0 - m), p1 = __expf(e1 - m), p2 = __expf(e2 - m);
    float s = p0 + p1 + p2;
    #pragma unroll
    for (int off = 32; off; off >>= 1) s += __shfl_xor(s, off, 64);
    float inv = 1.f / s;
    unsigned short* orow = att2 + (size_t)r * J_;
    orow[lane]       = f2bf(p0 * inv);
    orow[lane + 64]  = f2bf(p1 * inv);
    orow[lane + 128] = f2bf(p2 * inv);
}

// ---------------- K6: x-aggregation -> xAgg fp8. MODE 0 overwrite; MODE 1 RMW-accumulate ----------------
template <int MODE>
__global__ __launch_bounds__(512) void k6_agg(const unsigned short* __restrict__ att2,
                                              const unsigned short* __restrict__ Xsrc,
                                              unsigned char* __restrict__ xAgg8) {
    __shared__ alignas(16) unsigned short As[96][104];
    __shared__ alignas(16) unsigned short Bs[256][104];
    int t = threadIdx.x;
    int c0 = blockIdx.x * 256;
    int b = blockIdx.y / 96;
    int v = blockIdx.y % 96;
    size_t abase, astride;
    if (MODE == 0) { abase = ((size_t)(b * HW_) + (size_t)v * 96) * J_ + 96; astride = J_; }
    else           { abase = (size_t)(b * HW_) * J_ + (size_t)v * J_;        astride = (size_t)96 * J_; }
    if (t < 192) {
        int row = t >> 1, cs = (t & 1) * 6;
        const unsigned short* src = att2 + abase + (size_t)row * astride;
        #pragma unroll
        for (int i = 0; i < 6; ++i)
            *(uint4*)(&As[row][(cs + i) * 8]) = *(const uint4*)(src + (cs + i) * 8);
    }
    {
        int row = t >> 1, cs = (t & 1) * 6;
        const unsigned short* src = Xsrc + ((size_t)(b * C_) + c0 + row) * HW_ + v * 96;
        #pragma unroll
        for (int i = 0; i < 6; ++i)
            *(uint4*)(&Bs[row][(cs + i) * 8]) = *(const uint4*)(src + (cs + i) * 8);
    }
    __syncthreads();
    int wid = t >> 6, lane = t & 63;
    int wr = wid >> 2, wc = wid & 3;
    const f32x4 zero = {0.f, 0.f, 0.f, 0.f};
    f32x4 acc[3][4];
    for (int m = 0; m < 3; ++m) for (int n = 0; n < 4; ++n) acc[m][n] = zero;
    #pragma unroll
    for (int ks = 0; ks < 96; ks += 32) {
        int ko = ks + ((lane >> 4) << 3);
        short8 af[3], bfv[4];
        #pragma unroll
        for (int m = 0; m < 3; ++m) af[m] = *(const short8*)(&As[wr * 48 + m * 16 + (lane & 15)][ko]);
        #pragma unroll
        for (int n = 0; n < 4; ++n) bfv[n] = *(const short8*)(&Bs[wc * 64 + n * 16 + (lane & 15)][ko]);
        #pragma unroll
        for (int m = 0; m < 3; ++m)
            #pragma unroll
            for (int n = 0; n < 4; ++n)
                acc[m][n] = __builtin_amdgcn_mfma_f32_16x16x32_bf16(af[m], bfv[n], acc[m][n], 0, 0, 0);
    }
    #pragma unroll
    for (int m = 0; m < 3; ++m) {
        int orow = wr * 48 + m * 16 + ((lane >> 4) << 2);
        #pragma unroll
        for (int n = 0; n < 4; ++n) {
            int c = c0 + wc * 64 + n * 16 + (lane & 15);
            #pragma unroll
            for (int r = 0; r < 4; ++r) {
                int p = (MODE == 0) ? (v * 96 + orow + r) : ((orow + r) * 96 + v);
                size_t o = ((size_t)(b * HW_) + p) * C_ + c;
                if (MODE == 0) xAgg8[o] = f2fp8(acc[m][n][r]);
                else           xAgg8[o] = f2fp8(fp82f(xAgg8[o]) + acc[m][n][r]);
            }
        }
    }
}

// ---------------- K9: fp8 projection + epilogue, BK=32 dbuf counted-vmcnt + LDS-bounce ----------------
// acc = 16*Wv·xAgg (Wv pre-scaled); out = g*(acc/16 + bv) + bf2f(xP)
// BM=128(oc) BN=128(p) BK=32 dbuf fp8: staging LDS 16 KB, epilogue bounce 32 KB.
__global__ __launch_bounds__(256) void k9_proj(const unsigned char* __restrict__ xAgg8,
                                               const unsigned char* __restrict__ Wv8,
                                               const float* __restrict__ bv,
                                               const unsigned short* __restrict__ xPb,
                                               const float* __restrict__ gamma_p,
                                               float* __restrict__ outp) {
    __shared__ alignas(16) char smem[32768];
    int t = threadIdx.x;
    int bid = blockIdx.x;
    int tile = (bid & 7) * 288 + (bid >> 3);             // XCD-chunked remap (2304 = 8*288)
    int oc0 = (tile & 3) * 128;
    int pt  = tile >> 2;                                 // 0..575
    int p0  = pt * 128;
    int wid = t >> 6, lane = t & 63;
    int wr = wid >> 1, wc = wid & 1;                     // 2(oc:64) x 2(p:64)
    int srow = lane >> 1;                                // chunk: 32 rows x 32 B
    int sb = (lane & 1) * 16;
    const f32x4 zero = {0.f, 0.f, 0.f, 0.f};
    f32x4 acc[4][4];
    for (int m = 0; m < 4; ++m) for (int n = 0; n < 4; ++n) acc[m][n] = zero;

    // stage one BK=32 fp8 tile pair: A 4 chunks (1/wave) + B 4 chunks (1/wave) = 2 gl_lds/wave
    // A at smem[buf*4096], B at smem[8192 + buf*4096]
    auto STAGE = [&](int buf, int ks) {
        {
            int q = wid; int row = q * 32 + srow;
            gl_lds16(Wv8 + ((size_t)(oc0 + row) << 9) + ks + sb,
                     smem + buf * 4096 + q * 1024);
        }
        {
            int q = wid; int row = q * 32 + srow;
            gl_lds16(xAgg8 + ((size_t)(p0 + row) << 9) + ks + sb,
                     smem + 8192 + buf * 4096 + q * 1024);
        }
    };

    STAGE(0, 0);
    #pragma unroll
    for (int step = 0; step < 16; ++step) {
        int cur = step & 1;
        if (step < 15) {
            STAGE(cur ^ 1, (step + 1) * 32);             // prefetch next tile
            asm volatile("s_waitcnt vmcnt(2)" ::: "memory");   // cur's 2 loads done
        } else {
            asm volatile("s_waitcnt vmcnt(0)" ::: "memory");
        }
        __builtin_amdgcn_s_barrier();
        __builtin_amdgcn_sched_barrier(0);
        {
            long af[4], bfv[4];
            #pragma unroll
            for (int m = 0; m < 4; ++m) {
                int row = wr * 64 + m * 16 + (lane & 15);
                af[m] = *(const long*)(smem + cur * 4096 + row * 32 + ((lane >> 4) << 3));
            }
            #pragma unroll
            for (int n = 0; n < 4; ++n) {
                int row = wc * 64 + n * 16 + (lane & 15);
                bfv[n] = *(const long*)(smem + 8192 + cur * 4096 + row * 32 + ((lane >> 4) << 3));
            }
            #pragma unroll
            for (int m = 0; m < 4; ++m)
                #pragma unroll
                for (int n = 0; n < 4; ++n)
                    acc[m][n] = __builtin_amdgcn_mfma_f32_16x16x32_fp8_fp8(af[m], bfv[n], acc[m][n], 0, 0, 0);
        }
        __builtin_amdgcn_s_barrier();
    }
    __syncthreads();                                     // staging LDS dead; reuse for epilogue

    // Phase 1: acc/16 + bias -> bf16 tile [128 rows][128 cols], 16B-granule XOR swizzle
    #pragma unroll
    for (int m = 0; m < 4; ++m) {
        int rowb = wr * 64 + m * 16 + ((lane >> 4) << 2);
        #pragma unroll
        for (int r = 0; r < 4; ++r) {
            int row = rowb + r;
            float bias = bv[oc0 + row];
            #pragma unroll
            for (int n = 0; n < 4; ++n) {
                int col = wc * 64 + n * 16 + (lane & 15);
                int baddr = row * 256 + ((col << 1) ^ ((row & 7) << 4));
                *(unsigned short*)(smem + baddr) = f2bf(acc[m][n][r] * 0.0625f + bias);
            }
        }
    }
    __syncthreads();

    // Phase 2: coalesced write-out. 16 passes x (8 rows x 128 cols).
    int b = pt / 72;
    int hw0 = (pt % 72) * 128;
    float g = gamma_p[0];
    #pragma unroll
    for (int pass = 0; pass < 16; ++pass) {
        int row = pass * 8 + (t >> 5);
        int cs = (t & 31) * 4;
        uint2 tv = *(const uint2*)(smem + row * 256 + ((cs << 1) ^ ((row & 7) << 4)));
        int oc = oc0 + row;
        size_t o = ((size_t)(b * C_ + oc)) * HW_ + hw0 + cs;
        uint2 xv = *(const uint2*)(xPb + o);
        f32x4 ov;
        ov[0] = g * bf2f((unsigned short)(tv.x & 0xFFFF)) + bf2f((unsigned short)(xv.x & 0xFFFF));
        ov[1] = g * bf2f((unsigned short)(tv.x >> 16))    + bf2f((unsigned short)(xv.x >> 16));
        ov[2] = g * bf2f((unsigned short)(tv.y & 0xFFFF)) + bf2f((unsigned short)(xv.y & 0xFFFF));
        ov[3] = g * bf2f((unsigned short)(tv.y >> 16))    + bf2f((unsigned short)(xv.y >> 16));
        *(f32x4*)(outp + o) = ov;
    }
}

extern "C" void kernel_launch(void* const* d_in, const int* in_sizes, int n_in,
                              void* d_out, int out_size, void* d_ws, size_t ws_size,
                              hipStream_t stream) {
    const float* x  = (const float*)d_in[0];
    const float* Wq = (const float*)d_in[1];
    const float* bq = (const float*)d_in[2];
    const float* Wk = (const float*)d_in[3];
    const float* bk = (const float*)d_in[4];
    const float* Wv = (const float*)d_in[5];
    const float* bv = (const float*)d_in[6];
    const float* gm = (const float*)d_in[7];
    float* out = (float*)d_out;
    char* ws = (char*)d_ws;

    unsigned short* xT    = (unsigned short*)(ws + 0);
    unsigned char*  xAgg8 = (unsigned char*)(ws + 0);            // fp8, after k2a done
    unsigned short* xP    = (unsigned short*)(ws + 75497472);    // live k1 -> k9
    unsigned short* Qb    = (unsigned short*)(ws + 150994944);
    unsigned short* att2  = (unsigned short*)(ws + 150994944);   // after k4 done (overlays Qb/Kb)
    unsigned short* Kb    = (unsigned short*)(ws + 169869312);
    unsigned short* Wqk   = (unsigned short*)(ws + 188743680);
    unsigned*       Wv8u  = (unsigned*)(ws + 189005824);         // fp8 x16, 262,144 B
    // d_out scratch (dead before k9 writes out)
    unsigned short* attf  = (unsigned short*)d_out;              // fp16
    unsigned short* xPT   = (unsigned short*)((char*)d_out + 75497472);

    k0_wconv<<<768, 256, 0, stream>>>(Wq, Wk, Wv, Wqk, Wv8u);
    k1_xT<<<dim3(144, 8, 8), 256, 0, stream>>>(x, xT, xP);
    k2a_qk<<<576, 512, 0, stream>>>(xT, Wqk, bq, bk, Qb, Kb);
    k3_vt<<<4096, 256, 0, stream>>>(xP, xPT);
    k4_energy<<<dim3(96, 8, 2), 256, 0, stream>>>(Qb, Kb, attf);
    k5_softmax<<<18432, 256, 0, stream>>>(attf, att2);
    k6_agg<0><<<dim3(2, 768), 512, 0, stream>>>(att2, xP, xAgg8);   // xAgg8 overlays xT (dead)
    k6_agg<1><<<dim3(2, 768), 512, 0, stream>>>(att2, xPT, xAgg8);
    k9_proj<<<2304, 256, 0, stream>>>(xAgg8, (const unsigned char*)Wv8u, bv, xP, gm, out);
}

// Round 15
// 337.447 us; speedup vs baseline: 1.1312x; 1.0121x over previous
//
#include <hip/hip_runtime.h>

// CrissCrossAttention: B=8 C=512 CQ=128 H=W=96
// out = g*(Wv·xAgg + bv) + x, xAgg = attW·x + attH·x (linearity of V-path).
// ROUND 15: restore both-sides 16B-granule XOR swizzle in fp8 k9 staging/reads (rule 21).
// ws layout:
//  @0          : xT[p][512]bf16 75,497,472 (k1->k2a) THEN xAgg8[p][512]fp8 37,748,736 (k6->k9)
//  @75,497,472 : xP[b][c][h][w]bf16 75,497,472 (k1->k9)
//  @150,994,944: Qb[p][128]bf16 (k2a->k4); after k4: att2 bf16[p][192] (k5->k6)
//  @169,869,312: Kb[p][128]bf16 (k2a->k4)
//  @188,743,680: Wqk bf16[256][512]; @189,005,824: Wv8 fp8[512][512] (262,144 B)
// d_out scratch until k9: attf fp16 @0; xPT bf16 @75,497,472

#define B_ 8
#define C_ 512
#define CQ_ 128
#define H_ 96
#define W_ 96
#define HW_ 9216
#define J_ 192

typedef __attribute__((ext_vector_type(8))) short short8;
typedef __attribute__((ext_vector_type(4))) float f32x4;

__device__ __forceinline__ unsigned short f2bf(float f) {
    unsigned u = __float_as_uint(f);
    u += 0x7FFFu + ((u >> 16) & 1u);
    return (unsigned short)(u >> 16);
}
__device__ __forceinline__ float bf2f(unsigned short h) {
    return __uint_as_float((unsigned)h << 16);
}
__device__ __forceinline__ unsigned short f2h(float f) {
    _Float16 h = (_Float16)f;
    return __builtin_bit_cast(unsigned short, h);
}
__device__ __forceinline__ float h2f(unsigned short u) {
    return (float)__builtin_bit_cast(_Float16, u);
}
__device__ __forceinline__ unsigned char f2fp8(float v) {
    return (unsigned char)(__builtin_amdgcn_cvt_pk_fp8_f32(v, 0.f, 0, 0) & 0xFF);
}
__device__ __forceinline__ float fp82f(unsigned char v) {
    return __builtin_amdgcn_cvt_f32_fp8((int)v, 0);
}
__device__ __forceinline__ void gl_lds16(const void* g, void* lds_base) {
    __builtin_amdgcn_global_load_lds((const __attribute__((address_space(1))) void*)g,
                                     (__attribute__((address_space(3))) void*)lds_base,
                                     16, 0, 0);
}

// ---------------- K0: weights -> bf16 (Wqk) and fp8 x16 (Wv) ----------------
__global__ __launch_bounds__(256) void k0_wconv(const float* __restrict__ Wq,
                                                const float* __restrict__ Wk,
                                                const float* __restrict__ Wv,
                                                unsigned short* __restrict__ Wqk,
                                                unsigned* __restrict__ Wv8u) {
    int i = blockIdx.x * 256 + threadIdx.x;          // grid 768*256 = 196608
    if (i < 65536)        Wqk[i] = f2bf(Wq[i]);
    else if (i < 131072)  Wqk[i] = f2bf(Wk[i - 65536]);
    else {
        int j = (i - 131072) * 4;                    // 4 fp8 per thread
        int u = __builtin_amdgcn_cvt_pk_fp8_f32(Wv[j] * 16.f, Wv[j + 1] * 16.f, 0, 0);
        u = __builtin_amdgcn_cvt_pk_fp8_f32(Wv[j + 2] * 16.f, Wv[j + 3] * 16.f, u, 1);
        Wv8u[i - 131072] = (unsigned)u;
    }
}

// ---------------- K1: x f32 -> xT[b][hw][c] bf16 AND xP[b][c][hw] bf16 (vectorized) ----------------
__global__ __launch_bounds__(256) void k1_xT(const float* __restrict__ x,
                                             unsigned short* __restrict__ xT,
                                             unsigned short* __restrict__ xP) {
    __shared__ alignas(16) unsigned short tl[64][68];
    int b = blockIdx.z, c0 = blockIdx.y * 64, p0 = blockIdx.x * 64;
    int t = threadIdx.x;
    #pragma unroll
    for (int pass = 0; pass < 4; ++pass) {
        int m = t + pass * 256;
        int row = m >> 4, f4 = (m & 15) << 2;
        size_t off = ((size_t)(b * C_ + c0 + row)) * HW_ + p0 + f4;
        f32x4 v = *(const f32x4*)(x + off);
        uint2 o;
        o.x = (unsigned)f2bf(v[0]) | ((unsigned)f2bf(v[1]) << 16);
        o.y = (unsigned)f2bf(v[2]) | ((unsigned)f2bf(v[3]) << 16);
        *(uint2*)(xP + off) = o;
        *(uint2*)(&tl[row][f4]) = o;
    }
    __syncthreads();
    #pragma unroll
    for (int pass = 0; pass < 4; ++pass) {
        int m = t + pass * 256;
        int pr = m >> 4, cq = (m & 15) << 2;
        uint2 o;
        o.x = (unsigned)tl[cq + 0][pr] | ((unsigned)tl[cq + 1][pr] << 16);
        o.y = (unsigned)tl[cq + 2][pr] | ((unsigned)tl[cq + 3][pr] << 16);
        *(uint2*)(xT + ((size_t)(b * HW_ + p0 + pr)) * C_ + c0 + cq) = o;
    }
}

// ---------------- K3: plane transpose bf16 (vectorized globals) ----------------
__global__ __launch_bounds__(256) void k3_vt(const unsigned short* __restrict__ src_,
                                             unsigned short* __restrict__ dst_) {
    __shared__ unsigned short tl[96][97];
    int plane = blockIdx.x;
    const unsigned short* src = src_ + (size_t)plane * HW_;
    unsigned short* dst = dst_ + (size_t)plane * HW_;
    int t = threadIdx.x;
    for (int m = t; m < 1152; m += 256) {
        int h = m / 12, w8 = (m % 12) * 8;
        uint4 v = *(const uint4*)(src + h * 96 + w8);
        tl[h][w8 + 0] = (unsigned short)(v.x);
        tl[h][w8 + 1] = (unsigned short)(v.x >> 16);
        tl[h][w8 + 2] = (unsigned short)(v.y);
        tl[h][w8 + 3] = (unsigned short)(v.y >> 16);
        tl[h][w8 + 4] = (unsigned short)(v.z);
        tl[h][w8 + 5] = (unsigned short)(v.z >> 16);
        tl[h][w8 + 6] = (unsigned short)(v.w);
        tl[h][w8 + 7] = (unsigned short)(v.w >> 16);
    }
    __syncthreads();
    for (int m = t; m < 1152; m += 256) {
        int w = m / 12, h8 = (m % 12) * 8;
        uint4 o;
        o.x = (unsigned)tl[h8 + 0][w] | ((unsigned)tl[h8 + 1][w] << 16);
        o.y = (unsigned)tl[h8 + 2][w] | ((unsigned)tl[h8 + 3][w] << 16);
        o.z = (unsigned)tl[h8 + 4][w] | ((unsigned)tl[h8 + 5][w] << 16);
        o.w = (unsigned)tl[h8 + 6][w] | ((unsigned)tl[h8 + 7][w] << 16);
        *(uint4*)(dst + w * 96 + h8) = o;
    }
}

// ---------------- K2a: Q,K projection, BK=32 dbuf counted-vmcnt ----------------
__global__ __launch_bounds__(512) void k2a_qk(const unsigned short* __restrict__ xT,
                                              const unsigned short* __restrict__ Wqk,
                                              const float* __restrict__ bq,
                                              const float* __restrict__ bk,
                                              unsigned short* __restrict__ Qb,
                                              unsigned short* __restrict__ Kb) {
    __shared__ alignas(16) char smem[49152];
    unsigned short* AsBase = (unsigned short*)smem;            // [2][128][32] = 16 KB
    unsigned short* BsBase = (unsigned short*)(smem + 16384);  // [2][256][32] = 32 KB
    int t = threadIdx.x;
    int p0 = blockIdx.x * 128;
    int wid = t >> 6, lane = t & 63;
    int wr = wid >> 2, wc = wid & 3;
    int srow = lane >> 2;
    int sk8 = (((lane & 3) ^ (srow & 3)) << 3);
    const f32x4 zero = {0.f, 0.f, 0.f, 0.f};
    f32x4 acc[4][4];
    for (int m = 0; m < 4; ++m) for (int n = 0; n < 4; ++n) acc[m][n] = zero;

    auto STAGE = [&](int buf, int ks) {
        {
            int q = wid; int row = q * 16 + srow;
            gl_lds16(xT + ((size_t)(p0 + row) << 9) + ks + sk8,
                     smem + buf * 8192 + q * 1024);
        }
        #pragma unroll
        for (int i = 0; i < 2; ++i) {
            int q = wid * 2 + i; int row = q * 16 + srow;
            gl_lds16(Wqk + ((size_t)row << 9) + ks + sk8,
                     smem + 16384 + buf * 16384 + q * 1024);
        }
    };

    STAGE(0, 0);
    #pragma unroll
    for (int step = 0; step < 16; ++step) {
        int cur = step & 1;
        if (step < 15) {
            STAGE(cur ^ 1, (step + 1) * 32);
            asm volatile("s_waitcnt vmcnt(3)" ::: "memory");
        } else {
            asm volatile("s_waitcnt vmcnt(0)" ::: "memory");
        }
        __builtin_amdgcn_s_barrier();
        __builtin_amdgcn_sched_barrier(0);
        {
            short8 af[4], bfv[4];
            #pragma unroll
            for (int m = 0; m < 4; ++m) {
                int row = wr * 64 + m * 16 + (lane & 15);
                int po = (((lane >> 4) ^ (row & 3)) << 3);
                af[m] = *(const short8*)(AsBase + cur * 4096 + row * 32 + po);
            }
            #pragma unroll
            for (int n = 0; n < 4; ++n) {
                int row = wc * 64 + n * 16 + (lane & 15);
                int po = (((lane >> 4) ^ (row & 3)) << 3);
                bfv[n] = *(const short8*)(BsBase + cur * 8192 + row * 32 + po);
            }
            #pragma unroll
            for (int m = 0; m < 4; ++m)
                #pragma unroll
                for (int n = 0; n < 4; ++n)
                    acc[m][n] = __builtin_amdgcn_mfma_f32_16x16x32_bf16(af[m], bfv[n], acc[m][n], 0, 0, 0);
        }
        __builtin_amdgcn_s_barrier();
    }
    #pragma unroll
    for (int n = 0; n < 4; ++n) {
        int oc = wc * 64 + n * 16 + (lane & 15);
        float bias = (oc < 128) ? bq[oc] : bk[oc - 128];
        unsigned short* dst = (oc < 128) ? (Qb + oc) : (Kb + (oc - 128));
        #pragma unroll
        for (int m = 0; m < 4; ++m) {
            int pr = p0 + wr * 64 + m * 16 + ((lane >> 4) << 2);
            #pragma unroll
            for (int r = 0; r < 4; ++r)
                dst[(size_t)(pr + r) << 7] = f2bf(acc[m][n][r] + bias);
        }
    }
}

// ---------------- K4: energies (fp16 out). z=0: E_W; z=1: E_H (diag=-inf) ----------------
__global__ __launch_bounds__(256) void k4_energy(const unsigned short* __restrict__ Qb,
                                                 const unsigned short* __restrict__ Kb,
                                                 unsigned short* __restrict__ att) {
    __shared__ alignas(16) unsigned short Qs[96][136];
    __shared__ alignas(16) unsigned short Ks[96][136];
    int t = threadIdx.x;
    int modeH = blockIdx.z;
    int b = blockIdx.y, v0 = blockIdx.x;
    size_t base, rstride, obase_off, ostride;
    if (!modeH) {
        base      = (size_t)((b * H_ + v0) * W_) * CQ_;
        rstride   = CQ_;
        obase_off = (size_t)((b * H_ + v0) * W_) * J_ + H_;
        ostride   = J_;
    } else {
        base      = ((size_t)(b * H_) * W_ + v0) * CQ_;
        rstride   = (size_t)W_ * CQ_;
        obase_off = ((size_t)(b * H_) * W_ + v0) * J_;
        ostride   = (size_t)W_ * J_;
    }
    for (int q = t; q < 1536; q += 256) {
        int row = q >> 4, c8 = (q & 15) << 3;
        *(uint4*)(&Qs[row][c8]) = *(const uint4*)(Qb + base + (size_t)row * rstride + c8);
        *(uint4*)(&Ks[row][c8]) = *(const uint4*)(Kb + base + (size_t)row * rstride + c8);
    }
    __syncthreads();
    int wid = t >> 6, lane = t & 63;
    int wr = wid >> 1, wc = wid & 1;
    const f32x4 zero = {0.f, 0.f, 0.f, 0.f};
    f32x4 acc[3][3];
    for (int m = 0; m < 3; ++m) for (int n = 0; n < 3; ++n) acc[m][n] = zero;
    #pragma unroll
    for (int ks = 0; ks < 128; ks += 32) {
        int ko = ks + ((lane >> 4) << 3);
        short8 af[3], bfv[3];
        #pragma unroll
        for (int m = 0; m < 3; ++m) af[m] = *(const short8*)(&Qs[wr * 48 + m * 16 + (lane & 15)][ko]);
        #pragma unroll
        for (int n = 0; n < 3; ++n) bfv[n] = *(const short8*)(&Ks[wc * 48 + n * 16 + (lane & 15)][ko]);
        #pragma unroll
        for (int m = 0; m < 3; ++m)
            #pragma unroll
            for (int n = 0; n < 3; ++n)
                acc[m][n] = __builtin_amdgcn_mfma_f32_16x16x32_bf16(af[m], bfv[n], acc[m][n], 0, 0, 0);
    }
    unsigned short* ob = att + obase_off;
    #pragma unroll
    for (int m = 0; m < 3; ++m) {
        int i = wr * 48 + m * 16 + ((lane >> 4) << 2);
        #pragma unroll
        for (int n = 0; n < 3; ++n) {
            int j = wc * 48 + n * 16 + (lane & 15);
            #pragma unroll
            for (int r = 0; r < 4; ++r) {
                float v = acc[m][n][r];
                if (modeH && (i + r) == j) v = -__builtin_inff();
                ob[(size_t)(i + r) * ostride + j] = f2h(v);
            }
        }
    }
}

// ---------------- K5: softmax over 192 (fp16 in) -> bf16 att2 ----------------
__global__ __launch_bounds__(256) void k5_softmax(const unsigned short* __restrict__ att,
                                                  unsigned short* __restrict__ att2) {
    int r = blockIdx.x * 4 + (threadIdx.x >> 6);
    int lane = threadIdx.x & 63;
    const unsigned short* row = att + (size_t)r * J_;
    float e0 = h2f(row[lane]), e1 = h2f(row[lane + 64]), e2 = h2f(row[lane + 128]);
    float m = fmaxf(e0, fmaxf(e1, e2));
    #pragma unroll
    for (int off = 32; off; off >>= 1) m = fmaxf(m, __shfl_xor(m, off, 64));
    float p0 = __expf(e0 - m), p1 = __expf(e1 - m), p2 = __expf(e2 - m);
    float s = p0 + p1 + p2;
    #pragma unroll
    for (int off = 32; off; off >>= 1) s += __shfl_xor(s, off, 64);
    float inv = 1.f / s;
    unsigned short* orow = att2 + (size_t)r * J_;
    orow[lane]       = f2bf(p0 * inv);
    orow[lane + 64]  = f2bf(p1 * inv);
    orow[lane + 128] = f2bf(p2 * inv);
}

// ---------------- K6: x-aggregation -> xAgg fp8. MODE 0 overwrite; MODE 1 RMW-accumulate ----------------
template <int MODE>
__global__ __launch_bounds__(512) void k6_agg(const unsigned short* __restrict__ att2,
                                              const unsigned short* __restrict__ Xsrc,
                                              unsigned char* __restrict__ xAgg8) {
    __shared__ alignas(16) unsigned short As[96][104];
    __shared__ alignas(16) unsigned short Bs[256][104];
    int t = threadIdx.x;
    int c0 = blockIdx.x * 256;
    int b = blockIdx.y / 96;
    int v = blockIdx.y % 96;
    size_t abase, astride;
    if (MODE == 0) { abase = ((size_t)(b * HW_) + (size_t)v * 96) * J_ + 96; astride = J_; }
    else           { abase = (size_t)(b * HW_) * J_ + (size_t)v * J_;        astride = (size_t)96 * J_; }
    if (t < 192) {
        int row = t >> 1, cs = (t & 1) * 6;
        const unsigned short* src = att2 + abase + (size_t)row * astride;
        #pragma unroll
        for (int i = 0; i < 6; ++i)
            *(uint4*)(&As[row][(cs + i) * 8]) = *(const uint4*)(src + (cs + i) * 8);
    }
    {
        int row = t >> 1, cs = (t & 1) * 6;
        const unsigned short* src = Xsrc + ((size_t)(b * C_) + c0 + row) * HW_ + v * 96;
        #pragma unroll
        for (int i = 0; i < 6; ++i)
            *(uint4*)(&Bs[row][(cs + i) * 8]) = *(const uint4*)(src + (cs + i) * 8);
    }
    __syncthreads();
    int wid = t >> 6, lane = t & 63;
    int wr = wid >> 2, wc = wid & 3;
    const f32x4 zero = {0.f, 0.f, 0.f, 0.f};
    f32x4 acc[3][4];
    for (int m = 0; m < 3; ++m) for (int n = 0; n < 4; ++n) acc[m][n] = zero;
    #pragma unroll
    for (int ks = 0; ks < 96; ks += 32) {
        int ko = ks + ((lane >> 4) << 3);
        short8 af[3], bfv[4];
        #pragma unroll
        for (int m = 0; m < 3; ++m) af[m] = *(const short8*)(&As[wr * 48 + m * 16 + (lane & 15)][ko]);
        #pragma unroll
        for (int n = 0; n < 4; ++n) bfv[n] = *(const short8*)(&Bs[wc * 64 + n * 16 + (lane & 15)][ko]);
        #pragma unroll
        for (int m = 0; m < 3; ++m)
            #pragma unroll
            for (int n = 0; n < 4; ++n)
                acc[m][n] = __builtin_amdgcn_mfma_f32_16x16x32_bf16(af[m], bfv[n], acc[m][n], 0, 0, 0);
    }
    #pragma unroll
    for (int m = 0; m < 3; ++m) {
        int orow = wr * 48 + m * 16 + ((lane >> 4) << 2);
        #pragma unroll
        for (int n = 0; n < 4; ++n) {
            int c = c0 + wc * 64 + n * 16 + (lane & 15);
            #pragma unroll
            for (int r = 0; r < 4; ++r) {
                int p = (MODE == 0) ? (v * 96 + orow + r) : ((orow + r) * 96 + v);
                size_t o = ((size_t)(b * HW_) + p) * C_ + c;
                if (MODE == 0) xAgg8[o] = f2fp8(acc[m][n][r]);
                else           xAgg8[o] = f2fp8(fp82f(xAgg8[o]) + acc[m][n][r]);
            }
        }
    }
}

// ---------------- K9: fp8 projection + epilogue, BK=32 dbuf counted-vmcnt, swizzled, LDS-bounce ----------------
// acc = 16*Wv·xAgg (Wv pre-scaled); out = g*(acc/16 + bv) + bf2f(xP)
// BM=128(oc) BN=128(p) BK=32 dbuf fp8. Both-sides 16B-granule XOR swizzle:
//  stage: lane's global slot-pair = (lane&1) ^ ((lane>>3)&1)   [row = lane>>1 within chunk]
//  read : byte = (slot<<3) ^ (((row>>2)&1)<<4)  -> 4-way conflict becomes 2-way (free).
__global__ __launch_bounds__(256) void k9_proj(const unsigned char* __restrict__ xAgg8,
                                               const unsigned char* __restrict__ Wv8,
                                               const float* __restrict__ bv,
                                               const unsigned short* __restrict__ xPb,
                                               const float* __restrict__ gamma_p,
                                               float* __restrict__ outp) {
    __shared__ alignas(16) char smem[32768];
    int t = threadIdx.x;
    int bid = blockIdx.x;
    int tile = (bid & 7) * 288 + (bid >> 3);             // XCD-chunked remap (2304 = 8*288)
    int oc0 = (tile & 3) * 128;
    int pt  = tile >> 2;                                 // 0..575
    int p0  = pt * 128;
    int wid = t >> 6, lane = t & 63;
    int wr = wid >> 1, wc = wid & 1;                     // 2(oc:64) x 2(p:64)
    int srow = lane >> 1;                                // chunk: 32 rows x 32 B
    int sb = (((lane & 1) ^ ((lane >> 3) & 1)) << 4);    // pre-swizzled global slot-pair
    const f32x4 zero = {0.f, 0.f, 0.f, 0.f};
    f32x4 acc[4][4];
    for (int m = 0; m < 4; ++m) for (int n = 0; n < 4; ++n) acc[m][n] = zero;

    auto STAGE = [&](int buf, int ks) {
        {
            int q = wid; int row = q * 32 + srow;
            gl_lds16(Wv8 + ((size_t)(oc0 + row) << 9) + ks + sb,
                     smem + buf * 4096 + q * 1024);
        }
        {
            int q = wid; int row = q * 32 + srow;
            gl_lds16(xAgg8 + ((size_t)(p0 + row) << 9) + ks + sb,
                     smem + 8192 + buf * 4096 + q * 1024);
        }
    };

    STAGE(0, 0);
    #pragma unroll
    for (int step = 0; step < 16; ++step) {
        int cur = step & 1;
        if (step < 15) {
            STAGE(cur ^ 1, (step + 1) * 32);             // prefetch next tile
            asm volatile("s_waitcnt vmcnt(2)" ::: "memory");   // cur's 2 loads done
        } else {
            asm volatile("s_waitcnt vmcnt(0)" ::: "memory");
        }
        __builtin_amdgcn_s_barrier();
        __builtin_amdgcn_sched_barrier(0);
        {
            long af[4], bfv[4];
            #pragma unroll
            for (int m = 0; m < 4; ++m) {
                int row = wr * 64 + m * 16 + (lane & 15);
                int po = (((lane >> 4) << 3)) ^ (((row >> 2) & 1) << 4);
                af[m] = *(const long*)(smem + cur * 4096 + row * 32 + po);
            }
            #pragma unroll
            for (int n = 0; n < 4; ++n) {
                int row = wc * 64 + n * 16 + (lane & 15);
                int po = (((lane >> 4) << 3)) ^ (((row >> 2) & 1) << 4);
                bfv[n] = *(const long*)(smem + 8192 + cur * 4096 + row * 32 + po);
            }
            #pragma unroll
            for (int m = 0; m < 4; ++m)
                #pragma unroll
                for (int n = 0; n < 4; ++n)
                    acc[m][n] = __builtin_amdgcn_mfma_f32_16x16x32_fp8_fp8(af[m], bfv[n], acc[m][n], 0, 0, 0);
        }
        __builtin_amdgcn_s_barrier();
    }
    __syncthreads();                                     // staging LDS dead; reuse for epilogue

    // Phase 1: acc/16 + bias -> bf16 tile [128 rows][128 cols], 16B-granule XOR swizzle
    #pragma unroll
    for (int m = 0; m < 4; ++m) {
        int rowb = wr * 64 + m * 16 + ((lane >> 4) << 2);
        #pragma unroll
        for (int r = 0; r < 4; ++r) {
            int row = rowb + r;
            float bias = bv[oc0 + row];
            #pragma unroll
            for (int n = 0; n < 4; ++n) {
                int col = wc * 64 + n * 16 + (lane & 15);
                int baddr = row * 256 + ((col << 1) ^ ((row & 7) << 4));
                *(unsigned short*)(smem + baddr) = f2bf(acc[m][n][r] * 0.0625f + bias);
            }
        }
    }
    __syncthreads();

    // Phase 2: coalesced write-out. 16 passes x (8 rows x 128 cols).
    int b = pt / 72;
    int hw0 = (pt % 72) * 128;
    float g = gamma_p[0];
    #pragma unroll
    for (int pass = 0; pass < 16; ++pass) {
        int row = pass * 8 + (t >> 5);
        int cs = (t & 31) * 4;
        uint2 tv = *(const uint2*)(smem + row * 256 + ((cs << 1) ^ ((row & 7) << 4)));
        int oc = oc0 + row;
        size_t o = ((size_t)(b * C_ + oc)) * HW_ + hw0 + cs;
        uint2 xv = *(const uint2*)(xPb + o);
        f32x4 ov;
        ov[0] = g * bf2f((unsigned short)(tv.x & 0xFFFF)) + bf2f((unsigned short)(xv.x & 0xFFFF));
        ov[1] = g * bf2f((unsigned short)(tv.x >> 16))    + bf2f((unsigned short)(xv.x >> 16));
        ov[2] = g * bf2f((unsigned short)(tv.y & 0xFFFF)) + bf2f((unsigned short)(xv.y & 0xFFFF));
        ov[3] = g * bf2f((unsigned short)(tv.y >> 16))    + bf2f((unsigned short)(xv.y >> 16));
        *(f32x4*)(outp + o) = ov;
    }
}

extern "C" void kernel_launch(void* const* d_in, const int* in_sizes, int n_in,
                              void* d_out, int out_size, void* d_ws, size_t ws_size,
                              hipStream_t stream) {
    const float* x  = (const float*)d_in[0];
    const float* Wq = (const float*)d_in[1];
    const float* bq = (const float*)d_in[2];
    const float* Wk = (const float*)d_in[3];
    const float* bk = (const float*)d_in[4];
    const float* Wv = (const float*)d_in[5];
    const float* bv = (const float*)d_in[6];
    const float* gm = (const float*)d_in[7];
    float* out = (float*)d_out;
    char* ws = (char*)d_ws;

    unsigned short* xT    = (unsigned short*)(ws + 0);
    unsigned char*  xAgg8 = (unsigned char*)(ws + 0);            // fp8, after k2a done
    unsigned short* xP    = (unsigned short*)(ws + 75497472);    // live k1 -> k9
    unsigned short* Qb    = (unsigned short*)(ws + 150994944);
    unsigned short* att2  = (unsigned short*)(ws + 150994944);   // after k4 done (overlays Qb/Kb)
    unsigned short* Kb    = (unsigned short*)(ws + 169869312);
    unsigned short* Wqk   = (unsigned short*)(ws + 188743680);
    unsigned*       Wv8u  = (unsigned*)(ws + 189005824);         // fp8 x16, 262,144 B
    // d_out scratch (dead before k9 writes out)
    unsigned short* attf  = (unsigned short*)d_out;              // fp16
    unsigned short* xPT   = (unsigned short*)((char*)d_out + 75497472);

    k0_wconv<<<768, 256, 0, stream>>>(Wq, Wk, Wv, Wqk, Wv8u);
    k1_xT<<<dim3(144, 8, 8), 256, 0, stream>>>(x, xT, xP);
    k2a_qk<<<576, 512, 0, stream>>>(xT, Wqk, bq, bk, Qb, Kb);
    k3_vt<<<4096, 256, 0, stream>>>(xP, xPT);
    k4_energy<<<dim3(96, 8, 2), 256, 0, stream>>>(Qb, Kb, attf);
    k5_softmax<<<18432, 256, 0, stream>>>(attf, att2);
    k6_agg<0><<<dim3(2, 768), 512, 0, stream>>>(att2, xP, xAgg8);   // xAgg8 overlays xT (dead)
    k6_agg<1><<<dim3(2, 768), 512, 0, stream>>>(att2, xPT, xAgg8);
    k9_proj<<<2304, 256, 0, stream>>>(xAgg8, (const unsigned char*)Wv8u, bv, xP, gm, out);
}

// Round 16
// 331.388 us; speedup vs baseline: 1.1519x; 1.0183x over previous
//
#include <hip/hip_runtime.h>

// CrissCrossAttention: B=8 C=512 CQ=128 H=W=96
// out = g*(Wv·xAgg + bv) + x, xAgg = attW·x + attH·x (linearity of V-path).
// ROUND 16: T5 s_setprio(1) around MFMA clusters in k9/k2a/k6 (multi-block-per-CU regime).
// ws layout:
//  @0          : xT[p][512]bf16 75,497,472 (k1->k2a) THEN xAgg8[p][512]fp8 37,748,736 (k6->k9)
//  @75,497,472 : xP[b][c][h][w]bf16 75,497,472 (k1->k9)
//  @150,994,944: Qb[p][128]bf16 (k2a->k4); after k4: att2 bf16[p][192] (k5->k6)
//  @169,869,312: Kb[p][128]bf16 (k2a->k4)
//  @188,743,680: Wqk bf16[256][512]; @189,005,824: Wv8 fp8[512][512] (262,144 B)
// d_out scratch until k9: attf fp16 @0; xPT bf16 @75,497,472

#define B_ 8
#define C_ 512
#define CQ_ 128
#define H_ 96
#define W_ 96
#define HW_ 9216
#define J_ 192

typedef __attribute__((ext_vector_type(8))) short short8;
typedef __attribute__((ext_vector_type(4))) float f32x4;

__device__ __forceinline__ unsigned short f2bf(float f) {
    unsigned u = __float_as_uint(f);
    u += 0x7FFFu + ((u >> 16) & 1u);
    return (unsigned short)(u >> 16);
}
__device__ __forceinline__ float bf2f(unsigned short h) {
    return __uint_as_float((unsigned)h << 16);
}
__device__ __forceinline__ unsigned short f2h(float f) {
    _Float16 h = (_Float16)f;
    return __builtin_bit_cast(unsigned short, h);
}
__device__ __forceinline__ float h2f(unsigned short u) {
    return (float)__builtin_bit_cast(_Float16, u);
}
__device__ __forceinline__ unsigned char f2fp8(float v) {
    return (unsigned char)(__builtin_amdgcn_cvt_pk_fp8_f32(v, 0.f, 0, 0) & 0xFF);
}
__device__ __forceinline__ float fp82f(unsigned char v) {
    return __builtin_amdgcn_cvt_f32_fp8((int)v, 0);
}
__device__ __forceinline__ void gl_lds16(const void* g, void* lds_base) {
    __builtin_amdgcn_global_load_lds((const __attribute__((address_space(1))) void*)g,
                                     (__attribute__((address_space(3))) void*)lds_base,
                                     16, 0, 0);
}

// ---------------- K0: weights -> bf16 (Wqk) and fp8 x16 (Wv) ----------------
__global__ __launch_bounds__(256) void k0_wconv(const float* __restrict__ Wq,
                                                const float* __restrict__ Wk,
                                                const float* __restrict__ Wv,
                                                unsigned short* __restrict__ Wqk,
                                                unsigned* __restrict__ Wv8u) {
    int i = blockIdx.x * 256 + threadIdx.x;          // grid 768*256 = 196608
    if (i < 65536)        Wqk[i] = f2bf(Wq[i]);
    else if (i < 131072)  Wqk[i] = f2bf(Wk[i - 65536]);
    else {
        int j = (i - 131072) * 4;                    // 4 fp8 per thread
        int u = __builtin_amdgcn_cvt_pk_fp8_f32(Wv[j] * 16.f, Wv[j + 1] * 16.f, 0, 0);
        u = __builtin_amdgcn_cvt_pk_fp8_f32(Wv[j + 2] * 16.f, Wv[j + 3] * 16.f, u, 1);
        Wv8u[i - 131072] = (unsigned)u;
    }
}

// ---------------- K1: x f32 -> xT[b][hw][c] bf16 AND xP[b][c][hw] bf16 (vectorized) ----------------
__global__ __launch_bounds__(256) void k1_xT(const float* __restrict__ x,
                                             unsigned short* __restrict__ xT,
                                             unsigned short* __restrict__ xP) {
    __shared__ alignas(16) unsigned short tl[64][68];
    int b = blockIdx.z, c0 = blockIdx.y * 64, p0 = blockIdx.x * 64;
    int t = threadIdx.x;
    #pragma unroll
    for (int pass = 0; pass < 4; ++pass) {
        int m = t + pass * 256;
        int row = m >> 4, f4 = (m & 15) << 2;
        size_t off = ((size_t)(b * C_ + c0 + row)) * HW_ + p0 + f4;
        f32x4 v = *(const f32x4*)(x + off);
        uint2 o;
        o.x = (unsigned)f2bf(v[0]) | ((unsigned)f2bf(v[1]) << 16);
        o.y = (unsigned)f2bf(v[2]) | ((unsigned)f2bf(v[3]) << 16);
        *(uint2*)(xP + off) = o;
        *(uint2*)(&tl[row][f4]) = o;
    }
    __syncthreads();
    #pragma unroll
    for (int pass = 0; pass < 4; ++pass) {
        int m = t + pass * 256;
        int pr = m >> 4, cq = (m & 15) << 2;
        uint2 o;
        o.x = (unsigned)tl[cq + 0][pr] | ((unsigned)tl[cq + 1][pr] << 16);
        o.y = (unsigned)tl[cq + 2][pr] | ((unsigned)tl[cq + 3][pr] << 16);
        *(uint2*)(xT + ((size_t)(b * HW_ + p0 + pr)) * C_ + c0 + cq) = o;
    }
}

// ---------------- K3: plane transpose bf16 (vectorized globals) ----------------
__global__ __launch_bounds__(256) void k3_vt(const unsigned short* __restrict__ src_,
                                             unsigned short* __restrict__ dst_) {
    __shared__ unsigned short tl[96][97];
    int plane = blockIdx.x;
    const unsigned short* src = src_ + (size_t)plane * HW_;
    unsigned short* dst = dst_ + (size_t)plane * HW_;
    int t = threadIdx.x;
    for (int m = t; m < 1152; m += 256) {
        int h = m / 12, w8 = (m % 12) * 8;
        uint4 v = *(const uint4*)(src + h * 96 + w8);
        tl[h][w8 + 0] = (unsigned short)(v.x);
        tl[h][w8 + 1] = (unsigned short)(v.x >> 16);
        tl[h][w8 + 2] = (unsigned short)(v.y);
        tl[h][w8 + 3] = (unsigned short)(v.y >> 16);
        tl[h][w8 + 4] = (unsigned short)(v.z);
        tl[h][w8 + 5] = (unsigned short)(v.z >> 16);
        tl[h][w8 + 6] = (unsigned short)(v.w);
        tl[h][w8 + 7] = (unsigned short)(v.w >> 16);
    }
    __syncthreads();
    for (int m = t; m < 1152; m += 256) {
        int w = m / 12, h8 = (m % 12) * 8;
        uint4 o;
        o.x = (unsigned)tl[h8 + 0][w] | ((unsigned)tl[h8 + 1][w] << 16);
        o.y = (unsigned)tl[h8 + 2][w] | ((unsigned)tl[h8 + 3][w] << 16);
        o.z = (unsigned)tl[h8 + 4][w] | ((unsigned)tl[h8 + 5][w] << 16);
        o.w = (unsigned)tl[h8 + 6][w] | ((unsigned)tl[h8 + 7][w] << 16);
        *(uint4*)(dst + w * 96 + h8) = o;
    }
}

// ---------------- K2a: Q,K projection, BK=32 dbuf counted-vmcnt + setprio ----------------
__global__ __launch_bounds__(512) void k2a_qk(const unsigned short* __restrict__ xT,
                                              const unsigned short* __restrict__ Wqk,
                                              const float* __restrict__ bq,
                                              const float* __restrict__ bk,
                                              unsigned short* __restrict__ Qb,
                                              unsigned short* __restrict__ Kb) {
    __shared__ alignas(16) char smem[49152];
    unsigned short* AsBase = (unsigned short*)smem;            // [2][128][32] = 16 KB
    unsigned short* BsBase = (unsigned short*)(smem + 16384);  // [2][256][32] = 32 KB
    int t = threadIdx.x;
    int p0 = blockIdx.x * 128;
    int wid = t >> 6, lane = t & 63;
    int wr = wid >> 2, wc = wid & 3;
    int srow = lane >> 2;
    int sk8 = (((lane & 3) ^ (srow & 3)) << 3);
    const f32x4 zero = {0.f, 0.f, 0.f, 0.f};
    f32x4 acc[4][4];
    for (int m = 0; m < 4; ++m) for (int n = 0; n < 4; ++n) acc[m][n] = zero;

    auto STAGE = [&](int buf, int ks) {
        {
            int q = wid; int row = q * 16 + srow;
            gl_lds16(xT + ((size_t)(p0 + row) << 9) + ks + sk8,
                     smem + buf * 8192 + q * 1024);
        }
        #pragma unroll
        for (int i = 0; i < 2; ++i) {
            int q = wid * 2 + i; int row = q * 16 + srow;
            gl_lds16(Wqk + ((size_t)row << 9) + ks + sk8,
                     smem + 16384 + buf * 16384 + q * 1024);
        }
    };

    STAGE(0, 0);
    #pragma unroll
    for (int step = 0; step < 16; ++step) {
        int cur = step & 1;
        if (step < 15) {
            STAGE(cur ^ 1, (step + 1) * 32);
            asm volatile("s_waitcnt vmcnt(3)" ::: "memory");
        } else {
            asm volatile("s_waitcnt vmcnt(0)" ::: "memory");
        }
        __builtin_amdgcn_s_barrier();
        __builtin_amdgcn_sched_barrier(0);
        {
            short8 af[4], bfv[4];
            #pragma unroll
            for (int m = 0; m < 4; ++m) {
                int row = wr * 64 + m * 16 + (lane & 15);
                int po = (((lane >> 4) ^ (row & 3)) << 3);
                af[m] = *(const short8*)(AsBase + cur * 4096 + row * 32 + po);
            }
            #pragma unroll
            for (int n = 0; n < 4; ++n) {
                int row = wc * 64 + n * 16 + (lane & 15);
                int po = (((lane >> 4) ^ (row & 3)) << 3);
                bfv[n] = *(const short8*)(BsBase + cur * 8192 + row * 32 + po);
            }
            __builtin_amdgcn_s_setprio(1);
            #pragma unroll
            for (int m = 0; m < 4; ++m)
                #pragma unroll
                for (int n = 0; n < 4; ++n)
                    acc[m][n] = __builtin_amdgcn_mfma_f32_16x16x32_bf16(af[m], bfv[n], acc[m][n], 0, 0, 0);
            __builtin_amdgcn_s_setprio(0);
        }
        __builtin_amdgcn_s_barrier();
    }
    #pragma unroll
    for (int n = 0; n < 4; ++n) {
        int oc = wc * 64 + n * 16 + (lane & 15);
        float bias = (oc < 128) ? bq[oc] : bk[oc - 128];
        unsigned short* dst = (oc < 128) ? (Qb + oc) : (Kb + (oc - 128));
        #pragma unroll
        for (int m = 0; m < 4; ++m) {
            int pr = p0 + wr * 64 + m * 16 + ((lane >> 4) << 2);
            #pragma unroll
            for (int r = 0; r < 4; ++r)
                dst[(size_t)(pr + r) << 7] = f2bf(acc[m][n][r] + bias);
        }
    }
}

// ---------------- K4: energies (fp16 out). z=0: E_W; z=1: E_H (diag=-inf) ----------------
__global__ __launch_bounds__(256) void k4_energy(const unsigned short* __restrict__ Qb,
                                                 const unsigned short* __restrict__ Kb,
                                                 unsigned short* __restrict__ att) {
    __shared__ alignas(16) unsigned short Qs[96][136];
    __shared__ alignas(16) unsigned short Ks[96][136];
    int t = threadIdx.x;
    int modeH = blockIdx.z;
    int b = blockIdx.y, v0 = blockIdx.x;
    size_t base, rstride, obase_off, ostride;
    if (!modeH) {
        base      = (size_t)((b * H_ + v0) * W_) * CQ_;
        rstride   = CQ_;
        obase_off = (size_t)((b * H_ + v0) * W_) * J_ + H_;
        ostride   = J_;
    } else {
        base      = ((size_t)(b * H_) * W_ + v0) * CQ_;
        rstride   = (size_t)W_ * CQ_;
        obase_off = ((size_t)(b * H_) * W_ + v0) * J_;
        ostride   = (size_t)W_ * J_;
    }
    for (int q = t; q < 1536; q += 256) {
        int row = q >> 4, c8 = (q & 15) << 3;
        *(uint4*)(&Qs[row][c8]) = *(const uint4*)(Qb + base + (size_t)row * rstride + c8);
        *(uint4*)(&Ks[row][c8]) = *(const uint4*)(Kb + base + (size_t)row * rstride + c8);
    }
    __syncthreads();
    int wid = t >> 6, lane = t & 63;
    int wr = wid >> 1, wc = wid & 1;
    const f32x4 zero = {0.f, 0.f, 0.f, 0.f};
    f32x4 acc[3][3];
    for (int m = 0; m < 3; ++m) for (int n = 0; n < 3; ++n) acc[m][n] = zero;
    #pragma unroll
    for (int ks = 0; ks < 128; ks += 32) {
        int ko = ks + ((lane >> 4) << 3);
        short8 af[3], bfv[3];
        #pragma unroll
        for (int m = 0; m < 3; ++m) af[m] = *(const short8*)(&Qs[wr * 48 + m * 16 + (lane & 15)][ko]);
        #pragma unroll
        for (int n = 0; n < 3; ++n) bfv[n] = *(const short8*)(&Ks[wc * 48 + n * 16 + (lane & 15)][ko]);
        #pragma unroll
        for (int m = 0; m < 3; ++m)
            #pragma unroll
            for (int n = 0; n < 3; ++n)
                acc[m][n] = __builtin_amdgcn_mfma_f32_16x16x32_bf16(af[m], bfv[n], acc[m][n], 0, 0, 0);
    }
    unsigned short* ob = att + obase_off;
    #pragma unroll
    for (int m = 0; m < 3; ++m) {
        int i = wr * 48 + m * 16 + ((lane >> 4) << 2);
        #pragma unroll
        for (int n = 0; n < 3; ++n) {
            int j = wc * 48 + n * 16 + (lane & 15);
            #pragma unroll
            for (int r = 0; r < 4; ++r) {
                float v = acc[m][n][r];
                if (modeH && (i + r) == j) v = -__builtin_inff();
                ob[(size_t)(i + r) * ostride + j] = f2h(v);
            }
        }
    }
}

// ---------------- K5: softmax over 192 (fp16 in) -> bf16 att2 ----------------
__global__ __launch_bounds__(256) void k5_softmax(const unsigned short* __restrict__ att,
                                                  unsigned short* __restrict__ att2) {
    int r = blockIdx.x * 4 + (threadIdx.x >> 6);
    int lane = threadIdx.x & 63;
    const unsigned short* row = att + (size_t)r * J_;
    float e0 = h2f(row[lane]), e1 = h2f(row[lane + 64]), e2 = h2f(row[lane + 128]);
    float m = fmaxf(e0, fmaxf(e1, e2));
    #pragma unroll
    for (int off = 32; off; off >>= 1) m = fmaxf(m, __shfl_xor(m, off, 64));
    float p0 = __expf(e0 - m), p1 = __expf(e1 - m), p2 = __expf(e2 - m);
    float s = p0 + p1 + p2;
    #pragma unroll
    for (int off = 32; off; off >>= 1) s += __shfl_xor(s, off, 64);
    float inv = 1.f / s;
    unsigned short* orow = att2 + (size_t)r * J_;
    orow[lane]       = f2bf(p0 * inv);
    orow[lane + 64]  = f2bf(p1 * inv);
    orow[lane + 128] = f2bf(p2 * inv);
}

// ---------------- K6: x-aggregation -> xAgg fp8. MODE 0 overwrite; MODE 1 RMW-accumulate ----------------
template <int MODE>
__global__ __launch_bounds__(512) void k6_agg(const unsigned short* __restrict__ att2,
                                              const unsigned short* __restrict__ Xsrc,
                                              unsigned char* __restrict__ xAgg8) {
    __shared__ alignas(16) unsigned short As[96][104];
    __shared__ alignas(16) unsigned short Bs[256][104];
    int t = threadIdx.x;
    int c0 = blockIdx.x * 256;
    int b = blockIdx.y / 96;
    int v = blockIdx.y % 96;
    size_t abase, astride;
    if (MODE == 0) { abase = ((size_t)(b * HW_) + (size_t)v * 96) * J_ + 96; astride = J_; }
    else           { abase = (size_t)(b * HW_) * J_ + (size_t)v * J_;        astride = (size_t)96 * J_; }
    if (t < 192) {
        int row = t >> 1, cs = (t & 1) * 6;
        const unsigned short* src = att2 + abase + (size_t)row * astride;
        #pragma unroll
        for (int i = 0; i < 6; ++i)
            *(uint4*)(&As[row][(cs + i) * 8]) = *(const uint4*)(src + (cs + i) * 8);
    }
    {
        int row = t >> 1, cs = (t & 1) * 6;
        const unsigned short* src = Xsrc + ((size_t)(b * C_) + c0 + row) * HW_ + v * 96;
        #pragma unroll
        for (int i = 0; i < 6; ++i)
            *(uint4*)(&Bs[row][(cs + i) * 8]) = *(const uint4*)(src + (cs + i) * 8);
    }
    __syncthreads();
    int wid = t >> 6, lane = t & 63;
    int wr = wid >> 2, wc = wid & 3;
    const f32x4 zero = {0.f, 0.f, 0.f, 0.f};
    f32x4 acc[3][4];
    for (int m = 0; m < 3; ++m) for (int n = 0; n < 4; ++n) acc[m][n] = zero;
    #pragma unroll
    for (int ks = 0; ks < 96; ks += 32) {
        int ko = ks + ((lane >> 4) << 3);
        short8 af[3], bfv[4];
        #pragma unroll
        for (int m = 0; m < 3; ++m) af[m] = *(const short8*)(&As[wr * 48 + m * 16 + (lane & 15)][ko]);
        #pragma unroll
        for (int n = 0; n < 4; ++n) bfv[n] = *(const short8*)(&Bs[wc * 64 + n * 16 + (lane & 15)][ko]);
        __builtin_amdgcn_s_setprio(1);
        #pragma unroll
        for (int m = 0; m < 3; ++m)
            #pragma unroll
            for (int n = 0; n < 4; ++n)
                acc[m][n] = __builtin_amdgcn_mfma_f32_16x16x32_bf16(af[m], bfv[n], acc[m][n], 0, 0, 0);
        __builtin_amdgcn_s_setprio(0);
    }
    #pragma unroll
    for (int m = 0; m < 3; ++m) {
        int orow = wr * 48 + m * 16 + ((lane >> 4) << 2);
        #pragma unroll
        for (int n = 0; n < 4; ++n) {
            int c = c0 + wc * 64 + n * 16 + (lane & 15);
            #pragma unroll
            for (int r = 0; r < 4; ++r) {
                int p = (MODE == 0) ? (v * 96 + orow + r) : ((orow + r) * 96 + v);
                size_t o = ((size_t)(b * HW_) + p) * C_ + c;
                if (MODE == 0) xAgg8[o] = f2fp8(acc[m][n][r]);
                else           xAgg8[o] = f2fp8(fp82f(xAgg8[o]) + acc[m][n][r]);
            }
        }
    }
}

// ---------------- K9: fp8 projection + epilogue, BK=32 dbuf counted-vmcnt, swizzled, LDS-bounce ----------------
// acc = 16*Wv·xAgg (Wv pre-scaled); out = g*(acc/16 + bv) + bf2f(xP)
__global__ __launch_bounds__(256) void k9_proj(const unsigned char* __restrict__ xAgg8,
                                               const unsigned char* __restrict__ Wv8,
                                               const float* __restrict__ bv,
                                               const unsigned short* __restrict__ xPb,
                                               const float* __restrict__ gamma_p,
                                               float* __restrict__ outp) {
    __shared__ alignas(16) char smem[32768];
    int t = threadIdx.x;
    int bid = blockIdx.x;
    int tile = (bid & 7) * 288 + (bid >> 3);             // XCD-chunked remap (2304 = 8*288)
    int oc0 = (tile & 3) * 128;
    int pt  = tile >> 2;                                 // 0..575
    int p0  = pt * 128;
    int wid = t >> 6, lane = t & 63;
    int wr = wid >> 1, wc = wid & 1;                     // 2(oc:64) x 2(p:64)
    int srow = lane >> 1;                                // chunk: 32 rows x 32 B
    int sb = (((lane & 1) ^ ((lane >> 3) & 1)) << 4);    // pre-swizzled global slot-pair
    const f32x4 zero = {0.f, 0.f, 0.f, 0.f};
    f32x4 acc[4][4];
    for (int m = 0; m < 4; ++m) for (int n = 0; n < 4; ++n) acc[m][n] = zero;

    auto STAGE = [&](int buf, int ks) {
        {
            int q = wid; int row = q * 32 + srow;
            gl_lds16(Wv8 + ((size_t)(oc0 + row) << 9) + ks + sb,
                     smem + buf * 4096 + q * 1024);
        }
        {
            int q = wid; int row = q * 32 + srow;
            gl_lds16(xAgg8 + ((size_t)(p0 + row) << 9) + ks + sb,
                     smem + 8192 + buf * 4096 + q * 1024);
        }
    };

    STAGE(0, 0);
    #pragma unroll
    for (int step = 0; step < 16; ++step) {
        int cur = step & 1;
        if (step < 15) {
            STAGE(cur ^ 1, (step + 1) * 32);             // prefetch next tile
            asm volatile("s_waitcnt vmcnt(2)" ::: "memory");   // cur's 2 loads done
        } else {
            asm volatile("s_waitcnt vmcnt(0)" ::: "memory");
        }
        __builtin_amdgcn_s_barrier();
        __builtin_amdgcn_sched_barrier(0);
        {
            long af[4], bfv[4];
            #pragma unroll
            for (int m = 0; m < 4; ++m) {
                int row = wr * 64 + m * 16 + (lane & 15);
                int po = (((lane >> 4) << 3)) ^ (((row >> 2) & 1) << 4);
                af[m] = *(const long*)(smem + cur * 4096 + row * 32 + po);
            }
            #pragma unroll
            for (int n = 0; n < 4; ++n) {
                int row = wc * 64 + n * 16 + (lane & 15);
                int po = (((lane >> 4) << 3)) ^ (((row >> 2) & 1) << 4);
                bfv[n] = *(const long*)(smem + 8192 + cur * 4096 + row * 32 + po);
            }
            __builtin_amdgcn_s_setprio(1);
            #pragma unroll
            for (int m = 0; m < 4; ++m)
                #pragma unroll
                for (int n = 0; n < 4; ++n)
                    acc[m][n] = __builtin_amdgcn_mfma_f32_16x16x32_fp8_fp8(af[m], bfv[n], acc[m][n], 0, 0, 0);
            __builtin_amdgcn_s_setprio(0);
        }
        __builtin_amdgcn_s_barrier();
    }
    __syncthreads();                                     // staging LDS dead; reuse for epilogue

    // Phase 1: acc/16 + bias -> bf16 tile [128 rows][128 cols], 16B-granule XOR swizzle
    #pragma unroll
    for (int m = 0; m < 4; ++m) {
        int rowb = wr * 64 + m * 16 + ((lane >> 4) << 2);
        #pragma unroll
        for (int r = 0; r < 4; ++r) {
            int row = rowb + r;
            float bias = bv[oc0 + row];
            #pragma unroll
            for (int n = 0; n < 4; ++n) {
                int col = wc * 64 + n * 16 + (lane & 15);
                int baddr = row * 256 + ((col << 1) ^ ((row & 7) << 4));
                *(unsigned short*)(smem + baddr) = f2bf(acc[m][n][r] * 0.0625f + bias);
            }
        }
    }
    __syncthreads();

    // Phase 2: coalesced write-out. 16 passes x (8 rows x 128 cols).
    int b = pt / 72;
    int hw0 = (pt % 72) * 128;
    float g = gamma_p[0];
    #pragma unroll
    for (int pass = 0; pass < 16; ++pass) {
        int row = pass * 8 + (t >> 5);
        int cs = (t & 31) * 4;
        uint2 tv = *(const uint2*)(smem + row * 256 + ((cs << 1) ^ ((row & 7) << 4)));
        int oc = oc0 + row;
        size_t o = ((size_t)(b * C_ + oc)) * HW_ + hw0 + cs;
        uint2 xv = *(const uint2*)(xPb + o);
        f32x4 ov;
        ov[0] = g * bf2f((unsigned short)(tv.x & 0xFFFF)) + bf2f((unsigned short)(xv.x & 0xFFFF));
        ov[1] = g * bf2f((unsigned short)(tv.x >> 16))    + bf2f((unsigned short)(xv.x >> 16));
        ov[2] = g * bf2f((unsigned short)(tv.y & 0xFFFF)) + bf2f((unsigned short)(xv.y & 0xFFFF));
        ov[3] = g * bf2f((unsigned short)(tv.y >> 16))    + bf2f((unsigned short)(xv.y >> 16));
        *(f32x4*)(outp + o) = ov;
    }
}

extern "C" void kernel_launch(void* const* d_in, const int* in_sizes, int n_in,
                              void* d_out, int out_size, void* d_ws, size_t ws_size,
                              hipStream_t stream) {
    const float* x  = (const float*)d_in[0];
    const float* Wq = (const float*)d_in[1];
    const float* bq = (const float*)d_in[2];
    const float* Wk = (const float*)d_in[3];
    const float* bk = (const float*)d_in[4];
    const float* Wv = (const float*)d_in[5];
    const float* bv = (const float*)d_in[6];
    const float* gm = (const float*)d_in[7];
    float* out = (float*)d_out;
    char* ws = (char*)d_ws;

    unsigned short* xT    = (unsigned short*)(ws + 0);
    unsigned char*  xAgg8 = (unsigned char*)(ws + 0);            // fp8, after k2a done
    unsigned short* xP    = (unsigned short*)(ws + 75497472);    // live k1 -> k9
    unsigned short* Qb    = (unsigned short*)(ws + 150994944);
    unsigned short* att2  = (unsigned short*)(ws + 150994944);   // after k4 done (overlays Qb/Kb)
    unsigned short* Kb    = (unsigned short*)(ws + 169869312);
    unsigned short* Wqk   = (unsigned short*)(ws + 188743680);
    unsigned*       Wv8u  = (unsigned*)(ws + 189005824);         // fp8 x16, 262,144 B
    // d_out scratch (dead before k9 writes out)
    unsigned short* attf  = (unsigned short*)d_out;              // fp16
    unsigned short* xPT   = (unsigned short*)((char*)d_out + 75497472);

    k0_wconv<<<768, 256, 0, stream>>>(Wq, Wk, Wv, Wqk, Wv8u);
    k1_xT<<<dim3(144, 8, 8), 256, 0, stream>>>(x, xT, xP);
    k2a_qk<<<576, 512, 0, stream>>>(xT, Wqk, bq, bk, Qb, Kb);
    k3_vt<<<4096, 256, 0, stream>>>(xP, xPT);
    k4_energy<<<dim3(96, 8, 2), 256, 0, stream>>>(Qb, Kb, attf);
    k5_softmax<<<18432, 256, 0, stream>>>(attf, att2);
    k6_agg<0><<<dim3(2, 768), 512, 0, stream>>>(att2, xP, xAgg8);   // xAgg8 overlays xT (dead)
    k6_agg<1><<<dim3(2, 768), 512, 0, stream>>>(att2, xPT, xAgg8);
    k9_proj<<<2304, 256, 0, stream>>>(xAgg8, (const unsigned char*)Wv8u, bv, xP, gm, out);
}